// Round 12
// baseline (2905.502 us; speedup 1.0000x reference)
//
#include <hip/hip_runtime.h>
#include <hip/hip_bf16.h>

typedef __hip_bfloat16 bf16;
typedef long long i64;
typedef unsigned short u16;
typedef __attribute__((ext_vector_type(8))) short bf16x8;   // MFMA A/B frag (8 bf16)
typedef __attribute__((ext_vector_type(4))) float f32x4;    // MFMA C/D frag + nt-access vector

#define EPSV 1e-5f

static __device__ __forceinline__ float ldf(const void* p, size_t i, int fb) {
  return fb ? __bfloat162float(((const bf16*)p)[i]) : ((const float*)p)[i];
}
static __device__ __forceinline__ u16 f2b(float f) {  // RNE f32->bf16 raw bits
  unsigned int u = __float_as_uint(f);
  u += 0x7FFF + ((u >> 16) & 1);
  return (u16)(u >> 16);
}
static __device__ __forceinline__ float rb2f(u16 u) {
  return __uint_as_float(((unsigned int)u) << 16);
}

// ---------------- dtype detectors ----------------

__global__ void detect_int_kernel(const int* __restrict__ w, int* __restrict__ flag) {
  __shared__ int nz;
  if (threadIdx.x == 0) nz = 0;
  __syncthreads();
  for (int i = threadIdx.x; i < 1024; i += 256)
    if (w[2 * i + 1] != 0) atomicAdd(&nz, 1);
  __syncthreads();
  if (threadIdx.x == 0) *flag = (nz == 0) ? 1 : 0;  // 1 => int64
}

__global__ void detect_float_kernel(const unsigned int* __restrict__ g, int* __restrict__ flag) {
  if (threadIdx.x == 0) *flag = (g[0] == 0x3F803F80u) ? 1 : 0;  // 1 => bf16
}

// ---------------- setup ----------------

__global__ void init_zero_kernel(int* __restrict__ degcnt, int* __restrict__ fill, int n) {
  int i = blockIdx.x * 256 + threadIdx.x;
  if (i < n) { degcnt[i] = 0; fill[i] = 0; }
}

// XCD dst-partitioned: slice k = blockIdx&7 handles dst in [lo,hi) so the
// counter/csr lines for that range live in ONE XCD's L2.
__global__ void deg_kernel(const void* __restrict__ ei, const int* __restrict__ flag,
                           int* __restrict__ degcnt, int e, int n) {
  int k = blockIdx.x & 7;
  int lo = (int)(((long long)n * k) >> 3);
  int hi = (int)(((long long)n * (k + 1)) >> 3);
  int stride = (gridDim.x >> 3) * 256;
  int fb64 = *flag;
  for (int i = (blockIdx.x >> 3) * 256 + threadIdx.x; i < e; i += stride) {
    int d;
    if (fb64) d = (int)__builtin_nontemporal_load(((const i64*)ei) + (size_t)e + i);
    else      d = __builtin_nontemporal_load(((const int*)ei) + (size_t)e + i);
    if (d >= lo && d < hi) atomicAdd(&degcnt[d], 1);
  }
}

__global__ void dinv_kernel(const int* __restrict__ degcnt, float* __restrict__ dinv, int n) {
  int i = blockIdx.x * 256 + threadIdx.x;
  if (i < n) dinv[i] = rsqrtf((float)degcnt[i] + 1.0f);
}

// ---- multi-block exclusive scan ----

__global__ void __launch_bounds__(256) scanA_kernel(const int* __restrict__ deg,
                                                    int* __restrict__ rp,
                                                    int* __restrict__ bsum, int n) {
  int base = blockIdx.x * 1024 + threadIdx.x * 4;
  int v0 = (base     < n) ? deg[base]     : 0;
  int v1 = (base + 1 < n) ? deg[base + 1] : 0;
  int v2 = (base + 2 < n) ? deg[base + 2] : 0;
  int v3 = (base + 3 < n) ? deg[base + 3] : 0;
  int ts = v0 + v1 + v2 + v3;
  __shared__ int ls[256];
  ls[threadIdx.x] = ts;
  __syncthreads();
  for (int off = 1; off < 256; off <<= 1) {
    int u = (threadIdx.x >= off) ? ls[threadIdx.x - off] : 0;
    __syncthreads();
    ls[threadIdx.x] += u;
    __syncthreads();
  }
  int run = ls[threadIdx.x] - ts;
  if (base     < n) rp[base]     = run; run += v0;
  if (base + 1 < n) rp[base + 1] = run; run += v1;
  if (base + 2 < n) rp[base + 2] = run; run += v2;
  if (base + 3 < n) rp[base + 3] = run;
  if (threadIdx.x == 255) bsum[blockIdx.x] = ls[255];
}

__global__ void __launch_bounds__(256) scanB_kernel(int* __restrict__ bsum, int* __restrict__ rp,
                                                    int nb, int n, int e) {
  __shared__ int ls[256];
  int t = threadIdx.x;
  int v = (t < nb) ? bsum[t] : 0;
  ls[t] = v;
  __syncthreads();
  for (int off = 1; off < 256; off <<= 1) {
    int u = (t >= off) ? ls[t - off] : 0;
    __syncthreads();
    ls[t] += u;
    __syncthreads();
  }
  if (t < nb) bsum[t] = ls[t] - v;  // exclusive
  if (t == 0) rp[n] = e;
}

__global__ void scanC_kernel(int* __restrict__ rp, const int* __restrict__ bsum, int n) {
  int i = blockIdx.x * 256 + threadIdx.x;
  if (i < n) rp[i] += bsum[i >> 10];
}

// XCD dst-partitioned fill: csr lines for a dst-range stay on one XCD; each
// 64B line accumulates its ~16 writes in L2 instead of 1-write-per-HBM-line.
__global__ void fill_kernel(const void* __restrict__ ei, const int* __restrict__ flag,
                            const int* __restrict__ row_ptr,
                            int* __restrict__ fill, int* __restrict__ csr_src, int e, int n) {
  int k = blockIdx.x & 7;
  int lo = (int)(((long long)n * k) >> 3);
  int hi = (int)(((long long)n * (k + 1)) >> 3);
  int stride = (gridDim.x >> 3) * 256;
  int fb64 = *flag;
  for (int i = (blockIdx.x >> 3) * 256 + threadIdx.x; i < e; i += stride) {
    int d;
    if (fb64) d = (int)__builtin_nontemporal_load(((const i64*)ei) + (size_t)e + i);
    else      d = __builtin_nontemporal_load(((const int*)ei) + (size_t)e + i);
    if (d < lo || d >= hi) continue;
    int s;
    if (fb64) s = (int)__builtin_nontemporal_load(((const i64*)ei) + i);
    else      s = __builtin_nontemporal_load(((const int*)ei) + i);
    int pos = row_ptr[d] + atomicAdd(&fill[d], 1);
    csr_src[pos] = s;
  }
}

// ---------------- conv_W -> global B-frag order (bf16) ----------------

__global__ void wfrag_kernel(const void* __restrict__ W, const int* __restrict__ fflag,
                             u16* __restrict__ wf, int total) {
  int fb = *fflag;
  int i = blockIdx.x * 256 + threadIdx.x;
  if (i >= total) return;
  int l = i >> 14, r = i & 16383;
  int k = r >> 7, nn = r & 127;
  int s = k >> 5, quad = (k >> 3) & 3, j = k & 7;
  int ct = nn >> 4, n16 = nn & 15;
  wf[(size_t)l * 16384 + (ct * 4 + s) * 512 + quad * 128 + n16 * 8 + j] = f2b(ldf(W, i, fb));
}

// ---------------- input projection + BN partial stats (no atomics) ----------------

__global__ void __launch_bounds__(256) inproj_stats_kernel(
    const void* __restrict__ x, const void* __restrict__ W, const void* __restrict__ b,
    const int* __restrict__ fflag, float* __restrict__ pre,
    float* __restrict__ pi, int n, int in_dim) {
  int fb = *fflag;
  int q = threadIdx.x & 31, g8 = threadIdx.x >> 5;
  int c = q * 4;
  float b0 = ldf(b, c, fb), b1 = ldf(b, c + 1, fb), b2v = ldf(b, c + 2, fb), b3 = ldf(b, c + 3, fb);
  float s0 = 0, s1 = 0, s2 = 0, s3 = 0, q0 = 0, q1 = 0, q2 = 0, q3 = 0;
  for (int node = blockIdx.x * 8 + g8; node < n; node += gridDim.x * 8) {
    float a0 = b0, a1 = b1, a2 = b2v, a3 = b3;
    for (int k = 0; k < in_dim; ++k) {
      float xv = ldf(x, (size_t)node * in_dim + k, fb);
      size_t w0 = (size_t)k * 128 + c;
      a0 = fmaf(xv, ldf(W, w0, fb), a0);
      a1 = fmaf(xv, ldf(W, w0 + 1, fb), a1);
      a2 = fmaf(xv, ldf(W, w0 + 2, fb), a2);
      a3 = fmaf(xv, ldf(W, w0 + 3, fb), a3);
    }
    *(float4*)(pre + (size_t)node * 128 + c) = make_float4(a0, a1, a2, a3);
    s0 += a0; s1 += a1; s2 += a2; s3 += a3;
    q0 = fmaf(a0, a0, q0); q1 = fmaf(a1, a1, q1); q2 = fmaf(a2, a2, q2); q3 = fmaf(a3, a3, q3);
  }
  __shared__ float4 SS[256], QQ[256];
  SS[threadIdx.x] = make_float4(s0, s1, s2, s3);
  QQ[threadIdx.x] = make_float4(q0, q1, q2, q3);
  __syncthreads();
  if (threadIdx.x < 32) {
    float4 a = SS[threadIdx.x], qq = QQ[threadIdx.x];
    for (int g = 1; g < 8; ++g) {
      float4 u = SS[g * 32 + threadIdx.x], w = QQ[g * 32 + threadIdx.x];
      a.x += u.x; a.y += u.y; a.z += u.z; a.w += u.w;
      qq.x += w.x; qq.y += w.y; qq.z += w.z; qq.w += w.w;
    }
    int cc = threadIdx.x * 4;
    *(float4*)(pi + (size_t)blockIdx.x * 256 + cc) = a;
    *(float4*)(pi + (size_t)blockIdx.x * 256 + 128 + cc) = qq;
  }
}

__global__ void finalize_inproj_kernel(const float* __restrict__ pi, int nb,
                                       const void* __restrict__ g, const void* __restrict__ beta,
                                       const int* __restrict__ fflag,
                                       float* __restrict__ scale, float* __restrict__ shift,
                                       float inv_n) {
  int fb = *fflag;
  int c = threadIdx.x;  // 128
  float s = 0.f, s2 = 0.f;
#pragma unroll 4
  for (int b = 0; b < nb; ++b) {
    s += pi[(size_t)b * 256 + c];
    s2 += pi[(size_t)b * 256 + 128 + c];
  }
  float mean = s * inv_n;
  float var = s2 * inv_n - mean * mean;
  float sc = ldf(g, c, fb) * rsqrtf(var + EPSV);
  scale[c] = sc;
  shift[c] = ldf(beta, c, fb) - mean * sc;
}

// ---------------- fused BN-apply(+residual) + MFMA GEMM (bf16), norm-folded ----------------
// u stored SLICE-MAJOR: u[ct][node][16] for XCD cache blocking. nt stores for u.

__global__ void __launch_bounds__(256) gemm_bn_kernel(
    const float* __restrict__ pre, float* __restrict__ hbuf,
    const float* __restrict__ scale, const float* __restrict__ shift,
    const u16* __restrict__ wfL, const float* __restrict__ dinv,
    u16* __restrict__ u, int n, int use_res) {
  __shared__ u16 At[4][2048];   // per-wave A tile in frag order: s*512 + lane*8
  int lane = threadIdx.x & 63;
  int wave = threadIdx.x >> 6;
  int n16 = lane & 15, quad = lane >> 4;
  u16* at = At[wave];
  int node = lane & 15;             // staging row
  int cgrp = lane >> 4;             // staging col group 0..3
  int ntiles = (n + 15) >> 4;
  for (int tile = blockIdx.x * 4 + wave; tile < ntiles; tile += gridDim.x * 4) {
    int n0 = tile * 16;
    int gn = n0 + node;
    // ---- stage hnew tile (frag order) ----
#pragma unroll
    for (int r = 0; r < 8; ++r) {
      int c4 = r * 4 + cgrp;        // 0..31
      int c = c4 * 4;
      float4 h4 = make_float4(0.f, 0.f, 0.f, 0.f);
      if (gn < n) {
        f32x4 pv = __builtin_nontemporal_load((const f32x4*)(pre + (size_t)gn * 128 + c));
        float4 sc = *(const float4*)(scale + c);
        float4 sh = *(const float4*)(shift + c);
        h4.x = fmaxf(fmaf(pv[0], sc.x, sh.x), 0.f);
        h4.y = fmaxf(fmaf(pv[1], sc.y, sh.y), 0.f);
        h4.z = fmaxf(fmaf(pv[2], sc.z, sh.z), 0.f);
        h4.w = fmaxf(fmaf(pv[3], sc.w, sh.w), 0.f);
        if (use_res) {
          float4 rv = *(const float4*)(hbuf + (size_t)gn * 128 + c);
          h4.x += rv.x; h4.y += rv.y; h4.z += rv.z; h4.w += rv.w;
        }
        *(float4*)(hbuf + (size_t)gn * 128 + c) = h4;
      }
      ushort4 uu;
      uu.x = f2b(h4.x); uu.y = f2b(h4.y); uu.z = f2b(h4.z); uu.w = f2b(h4.w);
      int s = c4 >> 3, qd = (c4 >> 1) & 3, j0 = (c4 & 1) * 4;
      *(ushort4*)(at + s * 512 + qd * 128 + node * 8 + j0) = uu;
    }
    __builtin_amdgcn_s_waitcnt(0);  // drain LDS writes (wave-local tile)
    // ---- MFMA: 4 K-steps x 8 col-tiles; B from global wf ----
    f32x4 acc[8];
#pragma unroll
    for (int ct = 0; ct < 8; ++ct) acc[ct] = (f32x4){0.f, 0.f, 0.f, 0.f};
#pragma unroll
    for (int s = 0; s < 4; ++s) {
      bf16x8 af = *(const bf16x8*)(at + s * 512 + lane * 8);
#pragma unroll
      for (int ct = 0; ct < 8; ++ct) {
        bf16x8 bfr = *(const bf16x8*)(wfL + (size_t)(ct * 4 + s) * 512 + lane * 8);
        acc[ct] = __builtin_amdgcn_mfma_f32_16x16x32_bf16(af, bfr, acc[ct], 0, 0, 0);
      }
    }
    // ---- store D scaled by dinv[row], slice-major, non-temporal ----
    float dv[4];
#pragma unroll
    for (int r = 0; r < 4; ++r) {
      int row = n0 + quad * 4 + r;
      dv[r] = (row < n) ? dinv[row] : 0.f;
    }
#pragma unroll
    for (int ct = 0; ct < 8; ++ct) {
#pragma unroll
      for (int r = 0; r < 4; ++r) {
        int row = n0 + quad * 4 + r;
        if (row < n)
          __builtin_nontemporal_store(f2b(acc[ct][r] * dv[r]),
                                      u + ((size_t)ct * n + row) * 16 + n16);
      }
    }
  }
}

// ---------------- fused gather, XCD-sliced, partial stats ----------------
// csr_src read non-temporally (don't evict the L2-resident u slice);
// pre written non-temporally.

__global__ void __launch_bounds__(256) gather_stats_kernel(
    const int* __restrict__ row_ptr, const int* __restrict__ csr_src,
    const u16* __restrict__ u, const float* __restrict__ dinv,
    const void* __restrict__ b, const int* __restrict__ fflag,
    float* __restrict__ pre, float* __restrict__ pg, int n) {
  int fb = *fflag;
  int ct = blockIdx.x & 7;
  const u16* us = u + (size_t)ct * n * 16;
  int q = threadIdx.x & 1;           // 16B half
  int g = threadIdx.x >> 1;          // node group 0..127
  int c = ct * 16 + q * 8;           // global channel base
  float bias[8];
#pragma unroll
  for (int i = 0; i < 8; ++i) bias[i] = ldf(b, c + i, fb);
  float sA[8], qA[8];
#pragma unroll
  for (int i = 0; i < 8; ++i) { sA[i] = 0.f; qA[i] = 0.f; }

  int nstride = (gridDim.x >> 3) * 128;
  for (int node = (blockIdx.x >> 3) * 128 + g; node < n; node += nstride) {
    float acc[8];
    ushort4 su = *(const ushort4*)(us + (size_t)node * 16 + q * 8);
    acc[0] = rb2f(su.x); acc[1] = rb2f(su.y); acc[2] = rb2f(su.z); acc[3] = rb2f(su.w);
    ushort4 su2 = *(const ushort4*)(us + (size_t)node * 16 + q * 8 + 4);
    acc[4] = rb2f(su2.x); acc[5] = rb2f(su2.y); acc[6] = rb2f(su2.z); acc[7] = rb2f(su2.w);
    int beg = row_ptr[node], end = row_ptr[node + 1];
    int j = beg;
    for (; j + 4 <= end; j += 4) {
      int iA = __builtin_nontemporal_load(csr_src + j);
      int iB = __builtin_nontemporal_load(csr_src + j + 1);
      int iC = __builtin_nontemporal_load(csr_src + j + 2);
      int iD = __builtin_nontemporal_load(csr_src + j + 3);
      uint4 UA = *(const uint4*)(us + (size_t)iA * 16 + q * 8);
      uint4 UB = *(const uint4*)(us + (size_t)iB * 16 + q * 8);
      uint4 UC = *(const uint4*)(us + (size_t)iC * 16 + q * 8);
      uint4 UD = *(const uint4*)(us + (size_t)iD * 16 + q * 8);
#define ACC(UU) \
      acc[0] += __uint_as_float(UU.x << 16); acc[1] += __uint_as_float(UU.x & 0xFFFF0000u); \
      acc[2] += __uint_as_float(UU.y << 16); acc[3] += __uint_as_float(UU.y & 0xFFFF0000u); \
      acc[4] += __uint_as_float(UU.z << 16); acc[5] += __uint_as_float(UU.z & 0xFFFF0000u); \
      acc[6] += __uint_as_float(UU.w << 16); acc[7] += __uint_as_float(UU.w & 0xFFFF0000u);
      ACC(UA) ACC(UB) ACC(UC) ACC(UD)
    }
    for (; j < end; ++j) {
      int iA = __builtin_nontemporal_load(csr_src + j);
      uint4 UA = *(const uint4*)(us + (size_t)iA * 16 + q * 8);
      ACC(UA)
    }
#undef ACC
    float dv = dinv[node];
    f32x4 o0, o1;
    o0[0] = fmaf(acc[0], dv, bias[0]); o0[1] = fmaf(acc[1], dv, bias[1]);
    o0[2] = fmaf(acc[2], dv, bias[2]); o0[3] = fmaf(acc[3], dv, bias[3]);
    o1[0] = fmaf(acc[4], dv, bias[4]); o1[1] = fmaf(acc[5], dv, bias[5]);
    o1[2] = fmaf(acc[6], dv, bias[6]); o1[3] = fmaf(acc[7], dv, bias[7]);
    __builtin_nontemporal_store(o0, (f32x4*)(pre + (size_t)node * 128 + c));
    __builtin_nontemporal_store(o1, (f32x4*)(pre + (size_t)node * 128 + c + 4));
    sA[0] += o0[0]; sA[1] += o0[1]; sA[2] += o0[2]; sA[3] += o0[3];
    sA[4] += o1[0]; sA[5] += o1[1]; sA[6] += o1[2]; sA[7] += o1[3];
    qA[0] = fmaf(o0[0], o0[0], qA[0]); qA[1] = fmaf(o0[1], o0[1], qA[1]);
    qA[2] = fmaf(o0[2], o0[2], qA[2]); qA[3] = fmaf(o0[3], o0[3], qA[3]);
    qA[4] = fmaf(o1[0], o1[0], qA[4]); qA[5] = fmaf(o1[1], o1[1], qA[5]);
    qA[6] = fmaf(o1[2], o1[2], qA[6]); qA[7] = fmaf(o1[3], o1[3], qA[7]);
  }
  // wave butterfly over node-groups (keep q invariant: xor masks even)
#pragma unroll
  for (int m = 2; m <= 32; m <<= 1) {
#pragma unroll
    for (int i = 0; i < 8; ++i) {
      sA[i] += __shfl_xor(sA[i], m, 64);
      qA[i] += __shfl_xor(qA[i], m, 64);
    }
  }
  __shared__ float SW[4][2][8], QW[4][2][8];
  int lane = threadIdx.x & 63, wv = threadIdx.x >> 6;
  if (lane < 2) {
#pragma unroll
    for (int i = 0; i < 8; ++i) { SW[wv][lane][i] = sA[i]; QW[wv][lane][i] = qA[i]; }
  }
  __syncthreads();
  if (threadIdx.x < 16) {
    int qq = threadIdx.x >> 3, i = threadIdx.x & 7;
    float a = SW[0][qq][i] + SW[1][qq][i] + SW[2][qq][i] + SW[3][qq][i];
    float b2 = QW[0][qq][i] + QW[1][qq][i] + QW[2][qq][i] + QW[3][qq][i];
    pg[(size_t)blockIdx.x * 32 + qq * 8 + i] = a;
    pg[(size_t)blockIdx.x * 32 + 16 + qq * 8 + i] = b2;
  }
}

__global__ void finalize_gather_kernel(const float* __restrict__ pg, int nbG,
                                       const void* __restrict__ g, const void* __restrict__ beta,
                                       const int* __restrict__ fflag,
                                       float* __restrict__ scale, float* __restrict__ shift,
                                       float inv_n, size_t off) {
  int fb = *fflag;
  int c = threadIdx.x;  // 128
  int ct = c >> 4, ic = c & 15;
  float s = 0.f, s2 = 0.f;
#pragma unroll 4
  for (int b = ct; b < nbG; b += 8) {
    s += pg[(size_t)b * 32 + ic];
    s2 += pg[(size_t)b * 32 + 16 + ic];
  }
  float mean = s * inv_n;
  float var = s2 * inv_n - mean * mean;
  float sc = ldf(g, off + c, fb) * rsqrtf(var + EPSV);
  scale[c] = sc;
  shift[c] = ldf(beta, off + c, fb) - mean * sc;
}

// ---------------- fused final: BN-apply + residual + policy MLP + pool partials ----------------

__global__ void __launch_bounds__(256) policy_pool_kernel(
    const float* __restrict__ pre, const float* __restrict__ hbuf,
    const float* __restrict__ scale, const float* __restrict__ shift,
    const void* __restrict__ pW1, const void* __restrict__ pb1,
    const void* __restrict__ pW2, const void* __restrict__ pb2,
    const int* __restrict__ fflag, float* __restrict__ pp,
    void* __restrict__ out, int n) {
  __shared__ float W1[128 * 32];
  __shared__ float B1v[32], W2v[32];
  int fb = *fflag;
  for (int i = threadIdx.x; i < 128 * 32; i += 256) W1[i] = ldf(pW1, i, fb);
  if (threadIdx.x < 32) {
    B1v[threadIdx.x] = ldf(pb1, threadIdx.x, fb);
    W2v[threadIdx.x] = ldf(pW2, threadIdx.x, fb);
  }
  __syncthreads();
  float bias2 = ldf(pb2, 0, fb);
  int q = threadIdx.x & 31, g8 = threadIdx.x >> 5;
  int c = q * 4;
  float4 sc = *(const float4*)(scale + c);
  float4 sh = *(const float4*)(shift + c);
  float cs0 = 0, cs1 = 0, cs2 = 0, cs3 = 0;
  for (int node = blockIdx.x * 8 + g8; node < n; node += gridDim.x * 8) {
    float4 p = *(const float4*)(pre + (size_t)node * 128 + c);
    float4 r = *(const float4*)(hbuf + (size_t)node * 128 + c);
    float4 h4;
    h4.x = fmaxf(fmaf(p.x, sc.x, sh.x), 0.f) + r.x;
    h4.y = fmaxf(fmaf(p.y, sc.y, sh.y), 0.f) + r.y;
    h4.z = fmaxf(fmaf(p.z, sc.z, sh.z), 0.f) + r.z;
    h4.w = fmaxf(fmaf(p.w, sc.w, sh.w), 0.f) + r.w;
    cs0 += h4.x; cs1 += h4.y; cs2 += h4.z; cs3 += h4.w;
    float acc = B1v[q];
#pragma unroll
    for (int k4 = 0; k4 < 32; ++k4) {
      float hx = __shfl(h4.x, k4, 32);
      float hy = __shfl(h4.y, k4, 32);
      float hz = __shfl(h4.z, k4, 32);
      float hw = __shfl(h4.w, k4, 32);
      int k = k4 * 4;
      acc = fmaf(hx, W1[k * 32 + q], acc);
      acc = fmaf(hy, W1[(k + 1) * 32 + q], acc);
      acc = fmaf(hz, W1[(k + 2) * 32 + q], acc);
      acc = fmaf(hw, W1[(k + 3) * 32 + q], acc);
    }
    acc = fmaxf(acc, 0.f) * W2v[q];
    for (int off = 16; off; off >>= 1) acc += __shfl_down(acc, off, 32);
    if (q == 0) {
      float v = acc + bias2;
      if (fb) ((bf16*)out)[node] = __float2bfloat16(v);
      else    ((float*)out)[node] = v;
    }
  }
  __shared__ float4 SS[256];
  SS[threadIdx.x] = make_float4(cs0, cs1, cs2, cs3);
  __syncthreads();
  if (threadIdx.x < 32) {
    float4 a = SS[threadIdx.x];
    for (int g = 1; g < 8; ++g) {
      float4 u = SS[g * 32 + threadIdx.x];
      a.x += u.x; a.y += u.y; a.z += u.z; a.w += u.w;
    }
    *(float4*)(pp + (size_t)blockIdx.x * 128 + threadIdx.x * 4) = a;
  }
}

__global__ void value_kernel(const float* __restrict__ pp, int nbP,
                             const void* __restrict__ vW1, const void* __restrict__ vb1,
                             const void* __restrict__ vW2, const void* __restrict__ vb2,
                             const int* __restrict__ fflag,
                             void* __restrict__ out, int n, float inv_n) {
  __shared__ float gs[128];
  int fb = *fflag;
  int c = threadIdx.x;  // 128 threads
  float s = 0.f;
#pragma unroll 8
  for (int b = 0; b < nbP; ++b) s += pp[(size_t)b * 128 + c];
  gs[c] = s;
  __syncthreads();
  if (c < 64) {
    float acc = ldf(vb1, c, fb);
    for (int k = 0; k < 128; ++k) acc = fmaf(gs[k] * inv_n, ldf(vW1, (size_t)k * 64 + c, fb), acc);
    acc = fmaxf(acc, 0.f);
    float v = acc * ldf(vW2, c, fb);
    for (int off = 32; off; off >>= 1) v += __shfl_down(v, off, 64);
    if (c == 0) {
      float r = tanhf(v + ldf(vb2, 0, fb));
      if (fb) ((bf16*)out)[n] = __float2bfloat16(r);
      else    ((float*)out)[n] = r;
    }
  }
}

// ---------------- host ----------------

extern "C" void kernel_launch(void* const* d_in, const int* in_sizes, int n_in,
                              void* d_out, int out_size, void* d_ws, size_t ws_size,
                              hipStream_t stream) {
  const void* x       = d_in[0];
  const void* ei      = d_in[1];
  const void* in_W    = d_in[3];
  const void* in_b    = d_in[4];
  const void* in_g    = d_in[5];
  const void* in_beta = d_in[6];
  const void* conv_W  = d_in[7];
  const void* conv_b  = d_in[8];
  const void* bn_g    = d_in[9];
  const void* bn_beta = d_in[10];
  const void* pW1     = d_in[11];
  const void* pb1     = d_in[12];
  const void* pW2     = d_in[13];
  const void* pb2     = d_in[14];
  const void* vW1     = d_in[15];
  const void* vb1     = d_in[16];
  const void* vW2     = d_in[17];
  const void* vb2     = d_in[18];

  const int H = 128;
  int in_dim = in_sizes[3] / H;        // 5
  int n      = in_sizes[0] / in_dim;   // 100000
  int e      = in_sizes[1] / 2;        // 3200000
  int L      = in_sizes[7] / (H * H);  // 6

  const int GS  = 2048;  // gather grid (multiple of 8)
  const int GI  = 512;   // inproj grid
  const int GP  = 1024;  // policy grid
  const int GF  = 2048;  // fill/deg grid (multiple of 8)

  char* w = (char*)d_ws;
  u16*   u    = (u16*)w;   w += (size_t)n * H * sizeof(u16);
  float* pre  = (float*)w; w += (size_t)n * H * sizeof(float);
  float* hbuf = (float*)w; w += (size_t)n * H * sizeof(float);
  int*   csr_src  = (int*)w;   w += (size_t)e * sizeof(int);
  int*   row_ptr  = (int*)w;   w += (size_t)(n + 1 + 15) / 16 * 16 * sizeof(int);
  int*   degcnt   = (int*)w;   w += (size_t)n * sizeof(int);
  int*   fillc    = (int*)w;   w += (size_t)n * sizeof(int);
  float* dinv     = (float*)w; w += (size_t)n * sizeof(float);
  float* scale = (float*)w; w += 128 * sizeof(float);
  float* shift = (float*)w; w += 128 * sizeof(float);
  int*   eflag = (int*)w;   w += 16 * sizeof(int);
  int*   fflag = (int*)w;   w += 16 * sizeof(int);
  int*   bsum  = (int*)w;   w += 256 * sizeof(int);
  u16*   wf    = (u16*)w;   w += (size_t)L * H * H * sizeof(u16);
  float* pi    = (float*)w; w += (size_t)GI * 256 * sizeof(float);
  float* pg    = (float*)w; w += (size_t)GS * 32 * sizeof(float);
  float* pp    = (float*)w; w += (size_t)GP * 128 * sizeof(float);

  int gN = (n + 255) / 256;
  int nb = (n + 1023) >> 10;
  float inv_n = 1.0f / (float)n;

  detect_int_kernel<<<1, 256, 0, stream>>>((const int*)ei, eflag);
  detect_float_kernel<<<1, 64, 0, stream>>>((const unsigned int*)in_g, fflag);
  init_zero_kernel<<<gN, 256, 0, stream>>>(degcnt, fillc, n);
  deg_kernel<<<GF, 256, 0, stream>>>(ei, eflag, degcnt, e, n);
  dinv_kernel<<<gN, 256, 0, stream>>>(degcnt, dinv, n);
  scanA_kernel<<<nb, 256, 0, stream>>>(degcnt, row_ptr, bsum, n);
  scanB_kernel<<<1, 256, 0, stream>>>(bsum, row_ptr, nb, n, e);
  scanC_kernel<<<gN, 256, 0, stream>>>(row_ptr, bsum, n);
  fill_kernel<<<GF, 256, 0, stream>>>(ei, eflag, row_ptr, fillc, csr_src, e, n);
  wfrag_kernel<<<(L * H * H + 255) / 256, 256, 0, stream>>>(conv_W, fflag, wf, L * H * H);

  inproj_stats_kernel<<<GI, 256, 0, stream>>>(x, in_W, in_b, fflag, pre, pi, n, in_dim);
  finalize_inproj_kernel<<<1, 128, 0, stream>>>(pi, GI, in_g, in_beta, fflag, scale, shift, inv_n);

  for (int l = 0; l < L; ++l) {
    gemm_bn_kernel<<<1024, 256, 0, stream>>>(pre, hbuf, scale, shift, wf + (size_t)l * H * H,
                                             dinv, u, n, (l > 0) ? 1 : 0);
    gather_stats_kernel<<<GS, 256, 0, stream>>>(row_ptr, csr_src, u, dinv,
                                                conv_b, fflag, pre, pg, n);
    finalize_gather_kernel<<<1, 128, 0, stream>>>(pg, GS, bn_g, bn_beta, fflag, scale, shift,
                                                  inv_n, (size_t)l * H);
  }

  policy_pool_kernel<<<GP, 256, 0, stream>>>(pre, hbuf, scale, shift, pW1, pb1, pW2, pb2,
                                             fflag, pp, d_out, n);
  value_kernel<<<1, 128, 0, stream>>>(pp, GP, vW1, vb1, vW2, vb2, fflag, d_out, n, inv_n);
}

// Round 13
// 2286.418 us; speedup vs baseline: 1.2708x; 1.2708x over previous
//
#include <hip/hip_runtime.h>
#include <hip/hip_bf16.h>

typedef __hip_bfloat16 bf16;
typedef long long i64;
typedef unsigned short u16;
typedef __attribute__((ext_vector_type(8))) short bf16x8;   // MFMA A/B frag (8 bf16)
typedef __attribute__((ext_vector_type(4))) float f32x4;    // MFMA C/D frag

#define EPSV 1e-5f

static __device__ __forceinline__ float ldf(const void* p, size_t i, int fb) {
  return fb ? __bfloat162float(((const bf16*)p)[i]) : ((const float*)p)[i];
}
static __device__ __forceinline__ u16 f2b(float f) {  // RNE f32->bf16 raw bits
  unsigned int u = __float_as_uint(f);
  u += 0x7FFF + ((u >> 16) & 1);
  return (u16)(u >> 16);
}
static __device__ __forceinline__ float rb2f(u16 u) {
  return __uint_as_float(((unsigned int)u) << 16);
}

// ---------------- dtype detectors ----------------

__global__ void detect_int_kernel(const int* __restrict__ w, int* __restrict__ flag) {
  __shared__ int nz;
  if (threadIdx.x == 0) nz = 0;
  __syncthreads();
  for (int i = threadIdx.x; i < 1024; i += 256)
    if (w[2 * i + 1] != 0) atomicAdd(&nz, 1);
  __syncthreads();
  if (threadIdx.x == 0) *flag = (nz == 0) ? 1 : 0;  // 1 => int64
}

__global__ void detect_float_kernel(const unsigned int* __restrict__ g, int* __restrict__ flag) {
  if (threadIdx.x == 0) *flag = (g[0] == 0x3F803F80u) ? 1 : 0;  // 1 => bf16
}

// ---------------- setup ----------------

__global__ void init_zero_kernel(int* __restrict__ degcnt, int* __restrict__ fill, int n) {
  int i = blockIdx.x * 256 + threadIdx.x;
  if (i < n) { degcnt[i] = 0; fill[i] = 0; }
}

// XCD dst-partitioned: slice k = blockIdx&7 handles dst in [lo,hi) so the
// counter lines for that range live in ONE XCD's L2.
__global__ void deg_kernel(const void* __restrict__ ei, const int* __restrict__ flag,
                           int* __restrict__ degcnt, int e, int n) {
  int k = blockIdx.x & 7;
  int lo = (int)(((long long)n * k) >> 3);
  int hi = (int)(((long long)n * (k + 1)) >> 3);
  int stride = (gridDim.x >> 3) * 256;
  int fb64 = *flag;
  for (int i = (blockIdx.x >> 3) * 256 + threadIdx.x; i < e; i += stride) {
    int d;
    if (fb64) d = (int)((const i64*)ei)[(size_t)e + i];
    else      d = ((const int*)ei)[(size_t)e + i];
    if (d >= lo && d < hi) atomicAdd(&degcnt[d], 1);
  }
}

__global__ void dinv_kernel(const int* __restrict__ degcnt, float* __restrict__ dinv, int n) {
  int i = blockIdx.x * 256 + threadIdx.x;
  if (i < n) dinv[i] = rsqrtf((float)degcnt[i] + 1.0f);
}

// ---- multi-block exclusive scan ----

__global__ void __launch_bounds__(256) scanA_kernel(const int* __restrict__ deg,
                                                    int* __restrict__ rp,
                                                    int* __restrict__ bsum, int n) {
  int base = blockIdx.x * 1024 + threadIdx.x * 4;
  int v0 = (base     < n) ? deg[base]     : 0;
  int v1 = (base + 1 < n) ? deg[base + 1] : 0;
  int v2 = (base + 2 < n) ? deg[base + 2] : 0;
  int v3 = (base + 3 < n) ? deg[base + 3] : 0;
  int ts = v0 + v1 + v2 + v3;
  __shared__ int ls[256];
  ls[threadIdx.x] = ts;
  __syncthreads();
  for (int off = 1; off < 256; off <<= 1) {
    int u = (threadIdx.x >= off) ? ls[threadIdx.x - off] : 0;
    __syncthreads();
    ls[threadIdx.x] += u;
    __syncthreads();
  }
  int run = ls[threadIdx.x] - ts;
  if (base     < n) rp[base]     = run; run += v0;
  if (base + 1 < n) rp[base + 1] = run; run += v1;
  if (base + 2 < n) rp[base + 2] = run; run += v2;
  if (base + 3 < n) rp[base + 3] = run;
  if (threadIdx.x == 255) bsum[blockIdx.x] = ls[255];
}

__global__ void __launch_bounds__(256) scanB_kernel(int* __restrict__ bsum, int* __restrict__ rp,
                                                    int nb, int n, int e) {
  __shared__ int ls[256];
  int t = threadIdx.x;
  int v = (t < nb) ? bsum[t] : 0;
  ls[t] = v;
  __syncthreads();
  for (int off = 1; off < 256; off <<= 1) {
    int u = (t >= off) ? ls[t - off] : 0;
    __syncthreads();
    ls[t] += u;
    __syncthreads();
  }
  if (t < nb) bsum[t] = ls[t] - v;  // exclusive
  if (t == 0) rp[n] = e;
}

__global__ void scanC_kernel(int* __restrict__ rp, const int* __restrict__ bsum, int n) {
  int i = blockIdx.x * 256 + threadIdx.x;
  if (i < n) rp[i] += bsum[i >> 10];
}

// XCD dst-partitioned fill: csr lines for a dst-range stay on one XCD; each
// 64B line accumulates its ~16 writes in L2 instead of 1-write-per-HBM-line.
__global__ void fill_kernel(const void* __restrict__ ei, const int* __restrict__ flag,
                            const int* __restrict__ row_ptr,
                            int* __restrict__ fill, int* __restrict__ csr_src, int e, int n) {
  int k = blockIdx.x & 7;
  int lo = (int)(((long long)n * k) >> 3);
  int hi = (int)(((long long)n * (k + 1)) >> 3);
  int stride = (gridDim.x >> 3) * 256;
  int fb64 = *flag;
  for (int i = (blockIdx.x >> 3) * 256 + threadIdx.x; i < e; i += stride) {
    int d;
    if (fb64) d = (int)((const i64*)ei)[(size_t)e + i];
    else      d = ((const int*)ei)[(size_t)e + i];
    if (d < lo || d >= hi) continue;
    int s;
    if (fb64) s = (int)((const i64*)ei)[i];
    else      s = ((const int*)ei)[i];
    int pos = row_ptr[d] + atomicAdd(&fill[d], 1);
    csr_src[pos] = s;
  }
}

// ---------------- conv_W -> global B-frag order (bf16) ----------------

__global__ void wfrag_kernel(const void* __restrict__ W, const int* __restrict__ fflag,
                             u16* __restrict__ wf, int total) {
  int fb = *fflag;
  int i = blockIdx.x * 256 + threadIdx.x;
  if (i >= total) return;
  int l = i >> 14, r = i & 16383;
  int k = r >> 7, nn = r & 127;
  int s = k >> 5, quad = (k >> 3) & 3, j = k & 7;
  int ct = nn >> 4, n16 = nn & 15;
  wf[(size_t)l * 16384 + (ct * 4 + s) * 512 + quad * 128 + n16 * 8 + j] = f2b(ldf(W, i, fb));
}

// ---------------- input projection + BN partial stats (no atomics) ----------------

__global__ void __launch_bounds__(256) inproj_stats_kernel(
    const void* __restrict__ x, const void* __restrict__ W, const void* __restrict__ b,
    const int* __restrict__ fflag, float* __restrict__ pre,
    float* __restrict__ pi, int n, int in_dim) {
  int fb = *fflag;
  int q = threadIdx.x & 31, g8 = threadIdx.x >> 5;
  int c = q * 4;
  float b0 = ldf(b, c, fb), b1 = ldf(b, c + 1, fb), b2v = ldf(b, c + 2, fb), b3 = ldf(b, c + 3, fb);
  float s0 = 0, s1 = 0, s2 = 0, s3 = 0, q0 = 0, q1 = 0, q2 = 0, q3 = 0;
  for (int node = blockIdx.x * 8 + g8; node < n; node += gridDim.x * 8) {
    float a0 = b0, a1 = b1, a2 = b2v, a3 = b3;
    for (int k = 0; k < in_dim; ++k) {
      float xv = ldf(x, (size_t)node * in_dim + k, fb);
      size_t w0 = (size_t)k * 128 + c;
      a0 = fmaf(xv, ldf(W, w0, fb), a0);
      a1 = fmaf(xv, ldf(W, w0 + 1, fb), a1);
      a2 = fmaf(xv, ldf(W, w0 + 2, fb), a2);
      a3 = fmaf(xv, ldf(W, w0 + 3, fb), a3);
    }
    *(float4*)(pre + (size_t)node * 128 + c) = make_float4(a0, a1, a2, a3);
    s0 += a0; s1 += a1; s2 += a2; s3 += a3;
    q0 = fmaf(a0, a0, q0); q1 = fmaf(a1, a1, q1); q2 = fmaf(a2, a2, q2); q3 = fmaf(a3, a3, q3);
  }
  __shared__ float4 SS[256], QQ[256];
  SS[threadIdx.x] = make_float4(s0, s1, s2, s3);
  QQ[threadIdx.x] = make_float4(q0, q1, q2, q3);
  __syncthreads();
  if (threadIdx.x < 32) {
    float4 a = SS[threadIdx.x], qq = QQ[threadIdx.x];
    for (int g = 1; g < 8; ++g) {
      float4 u = SS[g * 32 + threadIdx.x], w = QQ[g * 32 + threadIdx.x];
      a.x += u.x; a.y += u.y; a.z += u.z; a.w += u.w;
      qq.x += w.x; qq.y += w.y; qq.z += w.z; qq.w += w.w;
    }
    int cc = threadIdx.x * 4;
    *(float4*)(pi + (size_t)blockIdx.x * 256 + cc) = a;
    *(float4*)(pi + (size_t)blockIdx.x * 256 + 128 + cc) = qq;
  }
}

__global__ void finalize_inproj_kernel(const float* __restrict__ pi, int nb,
                                       const void* __restrict__ g, const void* __restrict__ beta,
                                       const int* __restrict__ fflag,
                                       float* __restrict__ scale, float* __restrict__ shift,
                                       float inv_n) {
  int fb = *fflag;
  int c = threadIdx.x;  // 128
  float s = 0.f, s2 = 0.f;
#pragma unroll 4
  for (int b = 0; b < nb; ++b) {
    s += pi[(size_t)b * 256 + c];
    s2 += pi[(size_t)b * 256 + 128 + c];
  }
  float mean = s * inv_n;
  float var = s2 * inv_n - mean * mean;
  float sc = ldf(g, c, fb) * rsqrtf(var + EPSV);
  scale[c] = sc;
  shift[c] = ldf(beta, c, fb) - mean * sc;
}

// ---------------- fused BN-apply(+residual) + MFMA GEMM (bf16), norm-folded ----------------
// u stored SLICE-MAJOR: u[ct][node][16] for XCD cache blocking.

__global__ void __launch_bounds__(256) gemm_bn_kernel(
    const float* __restrict__ pre, float* __restrict__ hbuf,
    const float* __restrict__ scale, const float* __restrict__ shift,
    const u16* __restrict__ wfL, const float* __restrict__ dinv,
    u16* __restrict__ u, int n, int use_res) {
  __shared__ u16 At[4][2048];   // per-wave A tile in frag order: s*512 + lane*8
  int lane = threadIdx.x & 63;
  int wave = threadIdx.x >> 6;
  int n16 = lane & 15, quad = lane >> 4;
  u16* at = At[wave];
  int node = lane & 15;             // staging row
  int cgrp = lane >> 4;             // staging col group 0..3
  int ntiles = (n + 15) >> 4;
  for (int tile = blockIdx.x * 4 + wave; tile < ntiles; tile += gridDim.x * 4) {
    int n0 = tile * 16;
    int gn = n0 + node;
    // ---- stage hnew tile (frag order) ----
#pragma unroll
    for (int r = 0; r < 8; ++r) {
      int c4 = r * 4 + cgrp;        // 0..31
      int c = c4 * 4;
      float4 h4 = make_float4(0.f, 0.f, 0.f, 0.f);
      if (gn < n) {
        float4 p = *(const float4*)(pre + (size_t)gn * 128 + c);
        float4 sc = *(const float4*)(scale + c);
        float4 sh = *(const float4*)(shift + c);
        h4.x = fmaxf(fmaf(p.x, sc.x, sh.x), 0.f);
        h4.y = fmaxf(fmaf(p.y, sc.y, sh.y), 0.f);
        h4.z = fmaxf(fmaf(p.z, sc.z, sh.z), 0.f);
        h4.w = fmaxf(fmaf(p.w, sc.w, sh.w), 0.f);
        if (use_res) {
          float4 rv = *(const float4*)(hbuf + (size_t)gn * 128 + c);
          h4.x += rv.x; h4.y += rv.y; h4.z += rv.z; h4.w += rv.w;
        }
        *(float4*)(hbuf + (size_t)gn * 128 + c) = h4;
      }
      ushort4 uu;
      uu.x = f2b(h4.x); uu.y = f2b(h4.y); uu.z = f2b(h4.z); uu.w = f2b(h4.w);
      int s = c4 >> 3, qd = (c4 >> 1) & 3, j0 = (c4 & 1) * 4;
      *(ushort4*)(at + s * 512 + qd * 128 + node * 8 + j0) = uu;
    }
    __builtin_amdgcn_s_waitcnt(0);  // drain LDS writes (wave-local tile)
    // ---- MFMA: 4 K-steps x 8 col-tiles; B from global wf ----
    f32x4 acc[8];
#pragma unroll
    for (int ct = 0; ct < 8; ++ct) acc[ct] = (f32x4){0.f, 0.f, 0.f, 0.f};
#pragma unroll
    for (int s = 0; s < 4; ++s) {
      bf16x8 af = *(const bf16x8*)(at + s * 512 + lane * 8);
#pragma unroll
      for (int ct = 0; ct < 8; ++ct) {
        bf16x8 bfr = *(const bf16x8*)(wfL + (size_t)(ct * 4 + s) * 512 + lane * 8);
        acc[ct] = __builtin_amdgcn_mfma_f32_16x16x32_bf16(af, bfr, acc[ct], 0, 0, 0);
      }
    }
    // ---- store D scaled by dinv[row], slice-major ----
    float dv[4];
#pragma unroll
    for (int r = 0; r < 4; ++r) {
      int row = n0 + quad * 4 + r;
      dv[r] = (row < n) ? dinv[row] : 0.f;
    }
#pragma unroll
    for (int ct = 0; ct < 8; ++ct) {
#pragma unroll
      for (int r = 0; r < 4; ++r) {
        int row = n0 + quad * 4 + r;
        if (row < n) u[((size_t)ct * n + row) * 16 + n16] = f2b(acc[ct][r] * dv[r]);
      }
    }
  }
}

// ---------------- fused gather, XCD-sliced, partial stats ----------------

__global__ void __launch_bounds__(256) gather_stats_kernel(
    const int* __restrict__ row_ptr, const int* __restrict__ csr_src,
    const u16* __restrict__ u, const float* __restrict__ dinv,
    const void* __restrict__ b, const int* __restrict__ fflag,
    float* __restrict__ pre, float* __restrict__ pg, int n) {
  int fb = *fflag;
  int ct = blockIdx.x & 7;
  const u16* us = u + (size_t)ct * n * 16;
  int q = threadIdx.x & 1;           // 16B half
  int g = threadIdx.x >> 1;          // node group 0..127
  int c = ct * 16 + q * 8;           // global channel base
  float bias[8];
#pragma unroll
  for (int i = 0; i < 8; ++i) bias[i] = ldf(b, c + i, fb);
  float sA[8], qA[8];
#pragma unroll
  for (int i = 0; i < 8; ++i) { sA[i] = 0.f; qA[i] = 0.f; }

  int nstride = (gridDim.x >> 3) * 128;
  for (int node = (blockIdx.x >> 3) * 128 + g; node < n; node += nstride) {
    float acc[8];
    ushort4 su = *(const ushort4*)(us + (size_t)node * 16 + q * 8);
    acc[0] = rb2f(su.x); acc[1] = rb2f(su.y); acc[2] = rb2f(su.z); acc[3] = rb2f(su.w);
    ushort4 su2 = *(const ushort4*)(us + (size_t)node * 16 + q * 8 + 4);
    acc[4] = rb2f(su2.x); acc[5] = rb2f(su2.y); acc[6] = rb2f(su2.z); acc[7] = rb2f(su2.w);
    int beg = row_ptr[node], end = row_ptr[node + 1];
    int j = beg;
    for (; j + 4 <= end; j += 4) {
      int iA = csr_src[j], iB = csr_src[j + 1], iC = csr_src[j + 2], iD = csr_src[j + 3];
      uint4 UA = *(const uint4*)(us + (size_t)iA * 16 + q * 8);
      uint4 UB = *(const uint4*)(us + (size_t)iB * 16 + q * 8);
      uint4 UC = *(const uint4*)(us + (size_t)iC * 16 + q * 8);
      uint4 UD = *(const uint4*)(us + (size_t)iD * 16 + q * 8);
#define ACC(UU) \
      acc[0] += __uint_as_float(UU.x << 16); acc[1] += __uint_as_float(UU.x & 0xFFFF0000u); \
      acc[2] += __uint_as_float(UU.y << 16); acc[3] += __uint_as_float(UU.y & 0xFFFF0000u); \
      acc[4] += __uint_as_float(UU.z << 16); acc[5] += __uint_as_float(UU.z & 0xFFFF0000u); \
      acc[6] += __uint_as_float(UU.w << 16); acc[7] += __uint_as_float(UU.w & 0xFFFF0000u);
      ACC(UA) ACC(UB) ACC(UC) ACC(UD)
    }
    for (; j < end; ++j) {
      int iA = csr_src[j];
      uint4 UA = *(const uint4*)(us + (size_t)iA * 16 + q * 8);
      ACC(UA)
    }
#undef ACC
    float dv = dinv[node];
    float4 o0, o1;
    o0.x = fmaf(acc[0], dv, bias[0]); o0.y = fmaf(acc[1], dv, bias[1]);
    o0.z = fmaf(acc[2], dv, bias[2]); o0.w = fmaf(acc[3], dv, bias[3]);
    o1.x = fmaf(acc[4], dv, bias[4]); o1.y = fmaf(acc[5], dv, bias[5]);
    o1.z = fmaf(acc[6], dv, bias[6]); o1.w = fmaf(acc[7], dv, bias[7]);
    *(float4*)(pre + (size_t)node * 128 + c) = o0;
    *(float4*)(pre + (size_t)node * 128 + c + 4) = o1;
    sA[0] += o0.x; sA[1] += o0.y; sA[2] += o0.z; sA[3] += o0.w;
    sA[4] += o1.x; sA[5] += o1.y; sA[6] += o1.z; sA[7] += o1.w;
    qA[0] = fmaf(o0.x, o0.x, qA[0]); qA[1] = fmaf(o0.y, o0.y, qA[1]);
    qA[2] = fmaf(o0.z, o0.z, qA[2]); qA[3] = fmaf(o0.w, o0.w, qA[3]);
    qA[4] = fmaf(o1.x, o1.x, qA[4]); qA[5] = fmaf(o1.y, o1.y, qA[5]);
    qA[6] = fmaf(o1.z, o1.z, qA[6]); qA[7] = fmaf(o1.w, o1.w, qA[7]);
  }
  // wave butterfly over node-groups (keep q invariant: xor masks even)
#pragma unroll
  for (int m = 2; m <= 32; m <<= 1) {
#pragma unroll
    for (int i = 0; i < 8; ++i) {
      sA[i] += __shfl_xor(sA[i], m, 64);
      qA[i] += __shfl_xor(qA[i], m, 64);
    }
  }
  __shared__ float SW[4][2][8], QW[4][2][8];
  int lane = threadIdx.x & 63, wv = threadIdx.x >> 6;
  if (lane < 2) {
#pragma unroll
    for (int i = 0; i < 8; ++i) { SW[wv][lane][i] = sA[i]; QW[wv][lane][i] = qA[i]; }
  }
  __syncthreads();
  if (threadIdx.x < 16) {
    int qq = threadIdx.x >> 3, i = threadIdx.x & 7;
    float a = SW[0][qq][i] + SW[1][qq][i] + SW[2][qq][i] + SW[3][qq][i];
    float b2 = QW[0][qq][i] + QW[1][qq][i] + QW[2][qq][i] + QW[3][qq][i];
    pg[(size_t)blockIdx.x * 32 + qq * 8 + i] = a;
    pg[(size_t)blockIdx.x * 32 + 16 + qq * 8 + i] = b2;
  }
}

__global__ void finalize_gather_kernel(const float* __restrict__ pg, int nbG,
                                       const void* __restrict__ g, const void* __restrict__ beta,
                                       const int* __restrict__ fflag,
                                       float* __restrict__ scale, float* __restrict__ shift,
                                       float inv_n, size_t off) {
  int fb = *fflag;
  int c = threadIdx.x;  // 128
  int ct = c >> 4, ic = c & 15;
  float s = 0.f, s2 = 0.f;
#pragma unroll 4
  for (int b = ct; b < nbG; b += 8) {
    s += pg[(size_t)b * 32 + ic];
    s2 += pg[(size_t)b * 32 + 16 + ic];
  }
  float mean = s * inv_n;
  float var = s2 * inv_n - mean * mean;
  float sc = ldf(g, off + c, fb) * rsqrtf(var + EPSV);
  scale[c] = sc;
  shift[c] = ldf(beta, off + c, fb) - mean * sc;
}

// ---------------- fused final: BN-apply + residual + policy MLP + pool partials ----------------

__global__ void __launch_bounds__(256) policy_pool_kernel(
    const float* __restrict__ pre, const float* __restrict__ hbuf,
    const float* __restrict__ scale, const float* __restrict__ shift,
    const void* __restrict__ pW1, const void* __restrict__ pb1,
    const void* __restrict__ pW2, const void* __restrict__ pb2,
    const int* __restrict__ fflag, float* __restrict__ pp,
    void* __restrict__ out, int n) {
  __shared__ float W1[128 * 32];
  __shared__ float B1v[32], W2v[32];
  int fb = *fflag;
  for (int i = threadIdx.x; i < 128 * 32; i += 256) W1[i] = ldf(pW1, i, fb);
  if (threadIdx.x < 32) {
    B1v[threadIdx.x] = ldf(pb1, threadIdx.x, fb);
    W2v[threadIdx.x] = ldf(pW2, threadIdx.x, fb);
  }
  __syncthreads();
  float bias2 = ldf(pb2, 0, fb);
  int q = threadIdx.x & 31, g8 = threadIdx.x >> 5;
  int c = q * 4;
  float4 sc = *(const float4*)(scale + c);
  float4 sh = *(const float4*)(shift + c);
  float cs0 = 0, cs1 = 0, cs2 = 0, cs3 = 0;
  for (int node = blockIdx.x * 8 + g8; node < n; node += gridDim.x * 8) {
    float4 p = *(const float4*)(pre + (size_t)node * 128 + c);
    float4 r = *(const float4*)(hbuf + (size_t)node * 128 + c);
    float4 h4;
    h4.x = fmaxf(fmaf(p.x, sc.x, sh.x), 0.f) + r.x;
    h4.y = fmaxf(fmaf(p.y, sc.y, sh.y), 0.f) + r.y;
    h4.z = fmaxf(fmaf(p.z, sc.z, sh.z), 0.f) + r.z;
    h4.w = fmaxf(fmaf(p.w, sc.w, sh.w), 0.f) + r.w;
    cs0 += h4.x; cs1 += h4.y; cs2 += h4.z; cs3 += h4.w;
    float acc = B1v[q];
#pragma unroll
    for (int k4 = 0; k4 < 32; ++k4) {
      float hx = __shfl(h4.x, k4, 32);
      float hy = __shfl(h4.y, k4, 32);
      float hz = __shfl(h4.z, k4, 32);
      float hw = __shfl(h4.w, k4, 32);
      int k = k4 * 4;
      acc = fmaf(hx, W1[k * 32 + q], acc);
      acc = fmaf(hy, W1[(k + 1) * 32 + q], acc);
      acc = fmaf(hz, W1[(k + 2) * 32 + q], acc);
      acc = fmaf(hw, W1[(k + 3) * 32 + q], acc);
    }
    acc = fmaxf(acc, 0.f) * W2v[q];
    for (int off = 16; off; off >>= 1) acc += __shfl_down(acc, off, 32);
    if (q == 0) {
      float v = acc + bias2;
      if (fb) ((bf16*)out)[node] = __float2bfloat16(v);
      else    ((float*)out)[node] = v;
    }
  }
  __shared__ float4 SS[256];
  SS[threadIdx.x] = make_float4(cs0, cs1, cs2, cs3);
  __syncthreads();
  if (threadIdx.x < 32) {
    float4 a = SS[threadIdx.x];
    for (int g = 1; g < 8; ++g) {
      float4 u = SS[g * 32 + threadIdx.x];
      a.x += u.x; a.y += u.y; a.z += u.z; a.w += u.w;
    }
    *(float4*)(pp + (size_t)blockIdx.x * 128 + threadIdx.x * 4) = a;
  }
}

__global__ void value_kernel(const float* __restrict__ pp, int nbP,
                             const void* __restrict__ vW1, const void* __restrict__ vb1,
                             const void* __restrict__ vW2, const void* __restrict__ vb2,
                             const int* __restrict__ fflag,
                             void* __restrict__ out, int n, float inv_n) {
  __shared__ float gs[128];
  int fb = *fflag;
  int c = threadIdx.x;  // 128 threads
  float s = 0.f;
#pragma unroll 8
  for (int b = 0; b < nbP; ++b) s += pp[(size_t)b * 128 + c];
  gs[c] = s;
  __syncthreads();
  if (c < 64) {
    float acc = ldf(vb1, c, fb);
    for (int k = 0; k < 128; ++k) acc = fmaf(gs[k] * inv_n, ldf(vW1, (size_t)k * 64 + c, fb), acc);
    acc = fmaxf(acc, 0.f);
    float v = acc * ldf(vW2, c, fb);
    for (int off = 32; off; off >>= 1) v += __shfl_down(v, off, 64);
    if (c == 0) {
      float r = tanhf(v + ldf(vb2, 0, fb));
      if (fb) ((bf16*)out)[n] = __float2bfloat16(r);
      else    ((float*)out)[n] = r;
    }
  }
}

// ---------------- host ----------------

extern "C" void kernel_launch(void* const* d_in, const int* in_sizes, int n_in,
                              void* d_out, int out_size, void* d_ws, size_t ws_size,
                              hipStream_t stream) {
  const void* x       = d_in[0];
  const void* ei      = d_in[1];
  const void* in_W    = d_in[3];
  const void* in_b    = d_in[4];
  const void* in_g    = d_in[5];
  const void* in_beta = d_in[6];
  const void* conv_W  = d_in[7];
  const void* conv_b  = d_in[8];
  const void* bn_g    = d_in[9];
  const void* bn_beta = d_in[10];
  const void* pW1     = d_in[11];
  const void* pb1     = d_in[12];
  const void* pW2     = d_in[13];
  const void* pb2     = d_in[14];
  const void* vW1     = d_in[15];
  const void* vb1     = d_in[16];
  const void* vW2     = d_in[17];
  const void* vb2     = d_in[18];

  const int H = 128;
  int in_dim = in_sizes[3] / H;        // 5
  int n      = in_sizes[0] / in_dim;   // 100000
  int e      = in_sizes[1] / 2;        // 3200000
  int L      = in_sizes[7] / (H * H);  // 6

  const int GS  = 2048;  // gather grid (multiple of 8)
  const int GI  = 512;   // inproj grid
  const int GP  = 1024;  // policy grid
  const int GF  = 2048;  // fill/deg grid (multiple of 8)

  char* w = (char*)d_ws;
  u16*   u    = (u16*)w;   w += (size_t)n * H * sizeof(u16);
  float* pre  = (float*)w; w += (size_t)n * H * sizeof(float);
  float* hbuf = (float*)w; w += (size_t)n * H * sizeof(float);
  int*   csr_src  = (int*)w;   w += (size_t)e * sizeof(int);
  int*   row_ptr  = (int*)w;   w += (size_t)(n + 1 + 15) / 16 * 16 * sizeof(int);
  int*   degcnt   = (int*)w;   w += (size_t)n * sizeof(int);
  int*   fillc    = (int*)w;   w += (size_t)n * sizeof(int);
  float* dinv     = (float*)w; w += (size_t)n * sizeof(float);
  float* scale = (float*)w; w += 128 * sizeof(float);
  float* shift = (float*)w; w += 128 * sizeof(float);
  int*   eflag = (int*)w;   w += 16 * sizeof(int);
  int*   fflag = (int*)w;   w += 16 * sizeof(int);
  int*   bsum  = (int*)w;   w += 256 * sizeof(int);
  u16*   wf    = (u16*)w;   w += (size_t)L * H * H * sizeof(u16);
  float* pi    = (float*)w; w += (size_t)GI * 256 * sizeof(float);
  float* pg    = (float*)w; w += (size_t)GS * 32 * sizeof(float);
  float* pp    = (float*)w; w += (size_t)GP * 128 * sizeof(float);

  int gN = (n + 255) / 256;
  int nb = (n + 1023) >> 10;
  float inv_n = 1.0f / (float)n;

  detect_int_kernel<<<1, 256, 0, stream>>>((const int*)ei, eflag);
  detect_float_kernel<<<1, 64, 0, stream>>>((const unsigned int*)in_g, fflag);
  init_zero_kernel<<<gN, 256, 0, stream>>>(degcnt, fillc, n);
  deg_kernel<<<GF, 256, 0, stream>>>(ei, eflag, degcnt, e, n);
  dinv_kernel<<<gN, 256, 0, stream>>>(degcnt, dinv, n);
  scanA_kernel<<<nb, 256, 0, stream>>>(degcnt, row_ptr, bsum, n);
  scanB_kernel<<<1, 256, 0, stream>>>(bsum, row_ptr, nb, n, e);
  scanC_kernel<<<gN, 256, 0, stream>>>(row_ptr, bsum, n);
  fill_kernel<<<GF, 256, 0, stream>>>(ei, eflag, row_ptr, fillc, csr_src, e, n);
  wfrag_kernel<<<(L * H * H + 255) / 256, 256, 0, stream>>>(conv_W, fflag, wf, L * H * H);

  inproj_stats_kernel<<<GI, 256, 0, stream>>>(x, in_W, in_b, fflag, pre, pi, n, in_dim);
  finalize_inproj_kernel<<<1, 128, 0, stream>>>(pi, GI, in_g, in_beta, fflag, scale, shift, inv_n);

  for (int l = 0; l < L; ++l) {
    gemm_bn_kernel<<<1024, 256, 0, stream>>>(pre, hbuf, scale, shift, wf + (size_t)l * H * H,
                                             dinv, u, n, (l > 0) ? 1 : 0);
    gather_stats_kernel<<<GS, 256, 0, stream>>>(row_ptr, csr_src, u, dinv,
                                                conv_b, fflag, pre, pg, n);
    finalize_gather_kernel<<<1, 128, 0, stream>>>(pg, GS, bn_g, bn_beta, fflag, scale, shift,
                                                  inv_n, (size_t)l * H);
  }

  policy_pool_kernel<<<GP, 256, 0, stream>>>(pre, hbuf, scale, shift, pW1, pb1, pW2, pb2,
                                             fflag, pp, d_out, n);
  value_kernel<<<1, 128, 0, stream>>>(pp, GP, vW1, vb1, vW2, vb2, fflag, d_out, n, inv_n);
}

// Round 14
// 2172.832 us; speedup vs baseline: 1.3372x; 1.0523x over previous
//
#include <hip/hip_runtime.h>
#include <hip/hip_bf16.h>

typedef __hip_bfloat16 bf16;
typedef long long i64;
typedef unsigned short u16;
typedef __attribute__((ext_vector_type(8))) short bf16x8;   // MFMA A/B frag (8 bf16)
typedef __attribute__((ext_vector_type(4))) float f32x4;    // MFMA C/D frag

#define EPSV 1e-5f
#define WINLEN 6144   // staged csr window (24 KB LDS)

static __device__ __forceinline__ float ldf(const void* p, size_t i, int fb) {
  return fb ? __bfloat162float(((const bf16*)p)[i]) : ((const float*)p)[i];
}
static __device__ __forceinline__ u16 f2b(float f) {  // RNE f32->bf16 raw bits
  unsigned int u = __float_as_uint(f);
  u += 0x7FFF + ((u >> 16) & 1);
  return (u16)(u >> 16);
}
static __device__ __forceinline__ float rb2f(u16 u) {
  return __uint_as_float(((unsigned int)u) << 16);
}

// ---------------- dtype detectors ----------------

__global__ void detect_int_kernel(const int* __restrict__ w, int* __restrict__ flag) {
  __shared__ int nz;
  if (threadIdx.x == 0) nz = 0;
  __syncthreads();
  for (int i = threadIdx.x; i < 1024; i += 256)
    if (w[2 * i + 1] != 0) atomicAdd(&nz, 1);
  __syncthreads();
  if (threadIdx.x == 0) *flag = (nz == 0) ? 1 : 0;  // 1 => int64
}

__global__ void detect_float_kernel(const unsigned int* __restrict__ g, int* __restrict__ flag) {
  if (threadIdx.x == 0) *flag = (g[0] == 0x3F803F80u) ? 1 : 0;  // 1 => bf16
}

// ---------------- setup ----------------

__global__ void init_zero_kernel(int* __restrict__ degcnt, int* __restrict__ fill, int n) {
  int i = blockIdx.x * 256 + threadIdx.x;
  if (i < n) { degcnt[i] = 0; fill[i] = 0; }
}

// XCD dst-partitioned: slice k = blockIdx&7 handles dst in [lo,hi).
__global__ void deg_kernel(const void* __restrict__ ei, const int* __restrict__ flag,
                           int* __restrict__ degcnt, int e, int n) {
  int k = blockIdx.x & 7;
  int lo = (int)(((long long)n * k) >> 3);
  int hi = (int)(((long long)n * (k + 1)) >> 3);
  int stride = (gridDim.x >> 3) * 256;
  int fb64 = *flag;
  for (int i = (blockIdx.x >> 3) * 256 + threadIdx.x; i < e; i += stride) {
    int d;
    if (fb64) d = (int)((const i64*)ei)[(size_t)e + i];
    else      d = ((const int*)ei)[(size_t)e + i];
    if (d >= lo && d < hi) atomicAdd(&degcnt[d], 1);
  }
}

__global__ void dinv_kernel(const int* __restrict__ degcnt, float* __restrict__ dinv, int n) {
  int i = blockIdx.x * 256 + threadIdx.x;
  if (i < n) dinv[i] = rsqrtf((float)degcnt[i] + 1.0f);
}

// ---- multi-block exclusive scan ----

__global__ void __launch_bounds__(256) scanA_kernel(const int* __restrict__ deg,
                                                    int* __restrict__ rp,
                                                    int* __restrict__ bsum, int n) {
  int base = blockIdx.x * 1024 + threadIdx.x * 4;
  int v0 = (base     < n) ? deg[base]     : 0;
  int v1 = (base + 1 < n) ? deg[base + 1] : 0;
  int v2 = (base + 2 < n) ? deg[base + 2] : 0;
  int v3 = (base + 3 < n) ? deg[base + 3] : 0;
  int ts = v0 + v1 + v2 + v3;
  __shared__ int ls[256];
  ls[threadIdx.x] = ts;
  __syncthreads();
  for (int off = 1; off < 256; off <<= 1) {
    int u = (threadIdx.x >= off) ? ls[threadIdx.x - off] : 0;
    __syncthreads();
    ls[threadIdx.x] += u;
    __syncthreads();
  }
  int run = ls[threadIdx.x] - ts;
  if (base     < n) rp[base]     = run; run += v0;
  if (base + 1 < n) rp[base + 1] = run; run += v1;
  if (base + 2 < n) rp[base + 2] = run; run += v2;
  if (base + 3 < n) rp[base + 3] = run;
  if (threadIdx.x == 255) bsum[blockIdx.x] = ls[255];
}

__global__ void __launch_bounds__(256) scanB_kernel(int* __restrict__ bsum, int* __restrict__ rp,
                                                    int nb, int n, int e) {
  __shared__ int ls[256];
  int t = threadIdx.x;
  int v = (t < nb) ? bsum[t] : 0;
  ls[t] = v;
  __syncthreads();
  for (int off = 1; off < 256; off <<= 1) {
    int u = (t >= off) ? ls[t - off] : 0;
    __syncthreads();
    ls[t] += u;
    __syncthreads();
  }
  if (t < nb) bsum[t] = ls[t] - v;  // exclusive
  if (t == 0) rp[n] = e;
}

__global__ void scanC_kernel(int* __restrict__ rp, const int* __restrict__ bsum, int n) {
  int i = blockIdx.x * 256 + threadIdx.x;
  if (i < n) rp[i] += bsum[i >> 10];
}

// XCD dst-partitioned fill.
__global__ void fill_kernel(const void* __restrict__ ei, const int* __restrict__ flag,
                            const int* __restrict__ row_ptr,
                            int* __restrict__ fill, int* __restrict__ csr_src, int e, int n) {
  int k = blockIdx.x & 7;
  int lo = (int)(((long long)n * k) >> 3);
  int hi = (int)(((long long)n * (k + 1)) >> 3);
  int stride = (gridDim.x >> 3) * 256;
  int fb64 = *flag;
  for (int i = (blockIdx.x >> 3) * 256 + threadIdx.x; i < e; i += stride) {
    int d;
    if (fb64) d = (int)((const i64*)ei)[(size_t)e + i];
    else      d = ((const int*)ei)[(size_t)e + i];
    if (d < lo || d >= hi) continue;
    int s;
    if (fb64) s = (int)((const i64*)ei)[i];
    else      s = ((const int*)ei)[i];
    int pos = row_ptr[d] + atomicAdd(&fill[d], 1);
    csr_src[pos] = s;
  }
}

// ---------------- conv_W -> global B-frag order (bf16) ----------------

__global__ void wfrag_kernel(const void* __restrict__ W, const int* __restrict__ fflag,
                             u16* __restrict__ wf, int total) {
  int fb = *fflag;
  int i = blockIdx.x * 256 + threadIdx.x;
  if (i >= total) return;
  int l = i >> 14, r = i & 16383;
  int k = r >> 7, nn = r & 127;
  int s = k >> 5, quad = (k >> 3) & 3, j = k & 7;
  int ct = nn >> 4, n16 = nn & 15;
  wf[(size_t)l * 16384 + (ct * 4 + s) * 512 + quad * 128 + n16 * 8 + j] = f2b(ldf(W, i, fb));
}

// ---------------- input projection + BN partial stats (no atomics) ----------------

__global__ void __launch_bounds__(256) inproj_stats_kernel(
    const void* __restrict__ x, const void* __restrict__ W, const void* __restrict__ b,
    const int* __restrict__ fflag, float* __restrict__ pre,
    float* __restrict__ pi, int n, int in_dim) {
  int fb = *fflag;
  int q = threadIdx.x & 31, g8 = threadIdx.x >> 5;
  int c = q * 4;
  float b0 = ldf(b, c, fb), b1 = ldf(b, c + 1, fb), b2v = ldf(b, c + 2, fb), b3 = ldf(b, c + 3, fb);
  float s0 = 0, s1 = 0, s2 = 0, s3 = 0, q0 = 0, q1 = 0, q2 = 0, q3 = 0;
  for (int node = blockIdx.x * 8 + g8; node < n; node += gridDim.x * 8) {
    float a0 = b0, a1 = b1, a2 = b2v, a3 = b3;
    for (int k = 0; k < in_dim; ++k) {
      float xv = ldf(x, (size_t)node * in_dim + k, fb);
      size_t w0 = (size_t)k * 128 + c;
      a0 = fmaf(xv, ldf(W, w0, fb), a0);
      a1 = fmaf(xv, ldf(W, w0 + 1, fb), a1);
      a2 = fmaf(xv, ldf(W, w0 + 2, fb), a2);
      a3 = fmaf(xv, ldf(W, w0 + 3, fb), a3);
    }
    *(float4*)(pre + (size_t)node * 128 + c) = make_float4(a0, a1, a2, a3);
    s0 += a0; s1 += a1; s2 += a2; s3 += a3;
    q0 = fmaf(a0, a0, q0); q1 = fmaf(a1, a1, q1); q2 = fmaf(a2, a2, q2); q3 = fmaf(a3, a3, q3);
  }
  __shared__ float4 SS[256], QQ[256];
  SS[threadIdx.x] = make_float4(s0, s1, s2, s3);
  QQ[threadIdx.x] = make_float4(q0, q1, q2, q3);
  __syncthreads();
  if (threadIdx.x < 32) {
    float4 a = SS[threadIdx.x], qq = QQ[threadIdx.x];
    for (int g = 1; g < 8; ++g) {
      float4 u = SS[g * 32 + threadIdx.x], w = QQ[g * 32 + threadIdx.x];
      a.x += u.x; a.y += u.y; a.z += u.z; a.w += u.w;
      qq.x += w.x; qq.y += w.y; qq.z += w.z; qq.w += w.w;
    }
    int cc = threadIdx.x * 4;
    *(float4*)(pi + (size_t)blockIdx.x * 256 + cc) = a;
    *(float4*)(pi + (size_t)blockIdx.x * 256 + 128 + cc) = qq;
  }
}

__global__ void finalize_inproj_kernel(const float* __restrict__ pi, int nb,
                                       const void* __restrict__ g, const void* __restrict__ beta,
                                       const int* __restrict__ fflag,
                                       float* __restrict__ scale, float* __restrict__ shift,
                                       float inv_n) {
  int fb = *fflag;
  int c = threadIdx.x;  // 128
  float s = 0.f, s2 = 0.f;
#pragma unroll 4
  for (int b = 0; b < nb; ++b) {
    s += pi[(size_t)b * 256 + c];
    s2 += pi[(size_t)b * 256 + 128 + c];
  }
  float mean = s * inv_n;
  float var = s2 * inv_n - mean * mean;
  float sc = ldf(g, c, fb) * rsqrtf(var + EPSV);
  scale[c] = sc;
  shift[c] = ldf(beta, c, fb) - mean * sc;
}

// ---------------- fused BN-apply(+residual) + MFMA GEMM (bf16), norm-folded ----------------
// u stored SLICE-MAJOR: u[ct][node][16] for XCD cache blocking.

__global__ void __launch_bounds__(256) gemm_bn_kernel(
    const float* __restrict__ pre, float* __restrict__ hbuf,
    const float* __restrict__ scale, const float* __restrict__ shift,
    const u16* __restrict__ wfL, const float* __restrict__ dinv,
    u16* __restrict__ u, int n, int use_res) {
  __shared__ u16 At[4][2048];   // per-wave A tile in frag order: s*512 + lane*8
  int lane = threadIdx.x & 63;
  int wave = threadIdx.x >> 6;
  int n16 = lane & 15, quad = lane >> 4;
  u16* at = At[wave];
  int node = lane & 15;             // staging row
  int cgrp = lane >> 4;             // staging col group 0..3
  int ntiles = (n + 15) >> 4;
  for (int tile = blockIdx.x * 4 + wave; tile < ntiles; tile += gridDim.x * 4) {
    int n0 = tile * 16;
    int gn = n0 + node;
    // ---- stage hnew tile (frag order) ----
#pragma unroll
    for (int r = 0; r < 8; ++r) {
      int c4 = r * 4 + cgrp;        // 0..31
      int c = c4 * 4;
      float4 h4 = make_float4(0.f, 0.f, 0.f, 0.f);
      if (gn < n) {
        float4 p = *(const float4*)(pre + (size_t)gn * 128 + c);
        float4 sc = *(const float4*)(scale + c);
        float4 sh = *(const float4*)(shift + c);
        h4.x = fmaxf(fmaf(p.x, sc.x, sh.x), 0.f);
        h4.y = fmaxf(fmaf(p.y, sc.y, sh.y), 0.f);
        h4.z = fmaxf(fmaf(p.z, sc.z, sh.z), 0.f);
        h4.w = fmaxf(fmaf(p.w, sc.w, sh.w), 0.f);
        if (use_res) {
          float4 rv = *(const float4*)(hbuf + (size_t)gn * 128 + c);
          h4.x += rv.x; h4.y += rv.y; h4.z += rv.z; h4.w += rv.w;
        }
        *(float4*)(hbuf + (size_t)gn * 128 + c) = h4;
      }
      ushort4 uu;
      uu.x = f2b(h4.x); uu.y = f2b(h4.y); uu.z = f2b(h4.z); uu.w = f2b(h4.w);
      int s = c4 >> 3, qd = (c4 >> 1) & 3, j0 = (c4 & 1) * 4;
      *(ushort4*)(at + s * 512 + qd * 128 + node * 8 + j0) = uu;
    }
    __builtin_amdgcn_s_waitcnt(0);  // drain LDS writes (wave-local tile)
    // ---- MFMA: 4 K-steps x 8 col-tiles; B from global wf ----
    f32x4 acc[8];
#pragma unroll
    for (int ct = 0; ct < 8; ++ct) acc[ct] = (f32x4){0.f, 0.f, 0.f, 0.f};
#pragma unroll
    for (int s = 0; s < 4; ++s) {
      bf16x8 af = *(const bf16x8*)(at + s * 512 + lane * 8);
#pragma unroll
      for (int ct = 0; ct < 8; ++ct) {
        bf16x8 bfr = *(const bf16x8*)(wfL + (size_t)(ct * 4 + s) * 512 + lane * 8);
        acc[ct] = __builtin_amdgcn_mfma_f32_16x16x32_bf16(af, bfr, acc[ct], 0, 0, 0);
      }
    }
    // ---- store D scaled by dinv[row], slice-major ----
    float dv[4];
#pragma unroll
    for (int r = 0; r < 4; ++r) {
      int row = n0 + quad * 4 + r;
      dv[r] = (row < n) ? dinv[row] : 0.f;
    }
#pragma unroll
    for (int ct = 0; ct < 8; ++ct) {
#pragma unroll
      for (int r = 0; r < 4; ++r) {
        int row = n0 + quad * 4 + r;
        if (row < n) u[((size_t)ct * n + row) * 16 + n16] = f2b(acc[ct][r] * dv[r]);
      }
    }
  }
}

// ---------------- fused gather, XCD-sliced, LDS-staged nt csr, partial stats ----------------
// Block processes 128-node chunks; the chunk's contiguous csr range is staged
// into LDS with non-temporal loads (csr stream never evicts the L2-resident
// u slice). Thread pairs (2/node, 8ch each) consume indices from LDS.

__global__ void __launch_bounds__(256) gather_stats_kernel(
    const int* __restrict__ row_ptr, const int* __restrict__ csr_src,
    const u16* __restrict__ u, const float* __restrict__ dinv,
    const void* __restrict__ b, const int* __restrict__ fflag,
    float* __restrict__ pre, float* __restrict__ pg, int n, size_t bOff) {
  __shared__ int sm[WINLEN];
  __shared__ float SW[4][2][8], QW[4][2][8];
  int fb = *fflag;
  int ct = blockIdx.x & 7;
  const u16* us = u + (size_t)ct * n * 16;
  int q = threadIdx.x & 1;           // 16B half
  int g = threadIdx.x >> 1;          // node group 0..127
  int c = ct * 16 + q * 8;           // global channel base
  float bias[8];
#pragma unroll
  for (int i = 0; i < 8; ++i) bias[i] = ldf(b, bOff + c + i, fb);
  float sA[8], qA[8];
#pragma unroll
  for (int i = 0; i < 8; ++i) { sA[i] = 0.f; qA[i] = 0.f; }

  int chunk_stride = (gridDim.x >> 3) * 128;
  for (int c0 = (blockIdx.x >> 3) * 128; c0 < n; c0 += chunk_stride) {
    int node = c0 + g;
    int valid = node < n;
    int beg = valid ? row_ptr[node] : 0;
    int end = valid ? row_ptr[node + 1] : 0;
    int cend = c0 + 128; if (cend > n) cend = n;
    int chunk_lo = row_ptr[c0];
    int chunk_hi = row_ptr[cend];
    float acc[8];
    if (valid) {
      ushort4 su = *(const ushort4*)(us + (size_t)node * 16 + q * 8);
      acc[0] = rb2f(su.x); acc[1] = rb2f(su.y); acc[2] = rb2f(su.z); acc[3] = rb2f(su.w);
      ushort4 su2 = *(const ushort4*)(us + (size_t)node * 16 + q * 8 + 4);
      acc[4] = rb2f(su2.x); acc[5] = rb2f(su2.y); acc[6] = rb2f(su2.z); acc[7] = rb2f(su2.w);
    } else {
#pragma unroll
      for (int i = 0; i < 8; ++i) acc[i] = 0.f;
    }
    for (int wlo = chunk_lo; wlo < chunk_hi; wlo += WINLEN) {
      int wlen = chunk_hi - wlo; if (wlen > WINLEN) wlen = WINLEN;
      __syncthreads();   // previous window fully consumed
      for (int i = threadIdx.x; i < wlen; i += 256)
        sm[i] = __builtin_nontemporal_load(csr_src + wlo + i);
      __syncthreads();
      int j0 = beg > wlo ? beg : wlo;
      int j1 = end < wlo + wlen ? end : wlo + wlen;
      int j = j0;
      for (; j + 4 <= j1; j += 4) {
        int iA = sm[j - wlo], iB = sm[j - wlo + 1], iC = sm[j - wlo + 2], iD = sm[j - wlo + 3];
        uint4 UA = *(const uint4*)(us + (size_t)iA * 16 + q * 8);
        uint4 UB = *(const uint4*)(us + (size_t)iB * 16 + q * 8);
        uint4 UC = *(const uint4*)(us + (size_t)iC * 16 + q * 8);
        uint4 UD = *(const uint4*)(us + (size_t)iD * 16 + q * 8);
#define ACC(UU) \
        acc[0] += __uint_as_float(UU.x << 16); acc[1] += __uint_as_float(UU.x & 0xFFFF0000u); \
        acc[2] += __uint_as_float(UU.y << 16); acc[3] += __uint_as_float(UU.y & 0xFFFF0000u); \
        acc[4] += __uint_as_float(UU.z << 16); acc[5] += __uint_as_float(UU.z & 0xFFFF0000u); \
        acc[6] += __uint_as_float(UU.w << 16); acc[7] += __uint_as_float(UU.w & 0xFFFF0000u);
        ACC(UA) ACC(UB) ACC(UC) ACC(UD)
      }
      for (; j < j1; ++j) {
        int iA = sm[j - wlo];
        uint4 UA = *(const uint4*)(us + (size_t)iA * 16 + q * 8);
        ACC(UA)
      }
#undef ACC
    }
    if (valid) {
      float dv = dinv[node];
      float4 o0, o1;
      o0.x = fmaf(acc[0], dv, bias[0]); o0.y = fmaf(acc[1], dv, bias[1]);
      o0.z = fmaf(acc[2], dv, bias[2]); o0.w = fmaf(acc[3], dv, bias[3]);
      o1.x = fmaf(acc[4], dv, bias[4]); o1.y = fmaf(acc[5], dv, bias[5]);
      o1.z = fmaf(acc[6], dv, bias[6]); o1.w = fmaf(acc[7], dv, bias[7]);
      *(float4*)(pre + (size_t)node * 128 + c) = o0;
      *(float4*)(pre + (size_t)node * 128 + c + 4) = o1;
      sA[0] += o0.x; sA[1] += o0.y; sA[2] += o0.z; sA[3] += o0.w;
      sA[4] += o1.x; sA[5] += o1.y; sA[6] += o1.z; sA[7] += o1.w;
      qA[0] = fmaf(o0.x, o0.x, qA[0]); qA[1] = fmaf(o0.y, o0.y, qA[1]);
      qA[2] = fmaf(o0.z, o0.z, qA[2]); qA[3] = fmaf(o0.w, o0.w, qA[3]);
      qA[4] = fmaf(o1.x, o1.x, qA[4]); qA[5] = fmaf(o1.y, o1.y, qA[5]);
      qA[6] = fmaf(o1.z, o1.z, qA[6]); qA[7] = fmaf(o1.w, o1.w, qA[7]);
    }
  }
  // wave butterfly over node-groups (keep q invariant: xor masks even)
#pragma unroll
  for (int m = 2; m <= 32; m <<= 1) {
#pragma unroll
    for (int i = 0; i < 8; ++i) {
      sA[i] += __shfl_xor(sA[i], m, 64);
      qA[i] += __shfl_xor(qA[i], m, 64);
    }
  }
  int lane = threadIdx.x & 63, wv = threadIdx.x >> 6;
  if (lane < 2) {
#pragma unroll
    for (int i = 0; i < 8; ++i) { SW[wv][lane][i] = sA[i]; QW[wv][lane][i] = qA[i]; }
  }
  __syncthreads();
  if (threadIdx.x < 16) {
    int qq = threadIdx.x >> 3, i = threadIdx.x & 7;
    float a = SW[0][qq][i] + SW[1][qq][i] + SW[2][qq][i] + SW[3][qq][i];
    float b2 = QW[0][qq][i] + QW[1][qq][i] + QW[2][qq][i] + QW[3][qq][i];
    pg[(size_t)blockIdx.x * 32 + qq * 8 + i] = a;
    pg[(size_t)blockIdx.x * 32 + 16 + qq * 8 + i] = b2;
  }
}

__global__ void finalize_gather_kernel(const float* __restrict__ pg, int nbG,
                                       const void* __restrict__ g, const void* __restrict__ beta,
                                       const int* __restrict__ fflag,
                                       float* __restrict__ scale, float* __restrict__ shift,
                                       float inv_n, size_t off) {
  int fb = *fflag;
  int c = threadIdx.x;  // 128
  int ct = c >> 4, ic = c & 15;
  float s = 0.f, s2 = 0.f;
#pragma unroll 4
  for (int b = ct; b < nbG; b += 8) {
    s += pg[(size_t)b * 32 + ic];
    s2 += pg[(size_t)b * 32 + 16 + ic];
  }
  float mean = s * inv_n;
  float var = s2 * inv_n - mean * mean;
  float sc = ldf(g, off + c, fb) * rsqrtf(var + EPSV);
  scale[c] = sc;
  shift[c] = ldf(beta, off + c, fb) - mean * sc;
}

// ---------------- fused final: BN-apply + residual + policy MLP + pool partials ----------------

__global__ void __launch_bounds__(256) policy_pool_kernel(
    const float* __restrict__ pre, const float* __restrict__ hbuf,
    const float* __restrict__ scale, const float* __restrict__ shift,
    const void* __restrict__ pW1, const void* __restrict__ pb1,
    const void* __restrict__ pW2, const void* __restrict__ pb2,
    const int* __restrict__ fflag, float* __restrict__ pp,
    void* __restrict__ out, int n) {
  __shared__ float W1[128 * 32];
  __shared__ float B1v[32], W2v[32];
  int fb = *fflag;
  for (int i = threadIdx.x; i < 128 * 32; i += 256) W1[i] = ldf(pW1, i, fb);
  if (threadIdx.x < 32) {
    B1v[threadIdx.x] = ldf(pb1, threadIdx.x, fb);
    W2v[threadIdx.x] = ldf(pW2, threadIdx.x, fb);
  }
  __syncthreads();
  float bias2 = ldf(pb2, 0, fb);
  int q = threadIdx.x & 31, g8 = threadIdx.x >> 5;
  int c = q * 4;
  float4 sc = *(const float4*)(scale + c);
  float4 sh = *(const float4*)(shift + c);
  float cs0 = 0, cs1 = 0, cs2 = 0, cs3 = 0;
  for (int node = blockIdx.x * 8 + g8; node < n; node += gridDim.x * 8) {
    float4 p = *(const float4*)(pre + (size_t)node * 128 + c);
    float4 r = *(const float4*)(hbuf + (size_t)node * 128 + c);
    float4 h4;
    h4.x = fmaxf(fmaf(p.x, sc.x, sh.x), 0.f) + r.x;
    h4.y = fmaxf(fmaf(p.y, sc.y, sh.y), 0.f) + r.y;
    h4.z = fmaxf(fmaf(p.z, sc.z, sh.z), 0.f) + r.z;
    h4.w = fmaxf(fmaf(p.w, sc.w, sh.w), 0.f) + r.w;
    cs0 += h4.x; cs1 += h4.y; cs2 += h4.z; cs3 += h4.w;
    float acc = B1v[q];
#pragma unroll
    for (int k4 = 0; k4 < 32; ++k4) {
      float hx = __shfl(h4.x, k4, 32);
      float hy = __shfl(h4.y, k4, 32);
      float hz = __shfl(h4.z, k4, 32);
      float hw = __shfl(h4.w, k4, 32);
      int k = k4 * 4;
      acc = fmaf(hx, W1[k * 32 + q], acc);
      acc = fmaf(hy, W1[(k + 1) * 32 + q], acc);
      acc = fmaf(hz, W1[(k + 2) * 32 + q], acc);
      acc = fmaf(hw, W1[(k + 3) * 32 + q], acc);
    }
    acc = fmaxf(acc, 0.f) * W2v[q];
    for (int off = 16; off; off >>= 1) acc += __shfl_down(acc, off, 32);
    if (q == 0) {
      float v = acc + bias2;
      if (fb) ((bf16*)out)[node] = __float2bfloat16(v);
      else    ((float*)out)[node] = v;
    }
  }
  __shared__ float4 SS[256];
  SS[threadIdx.x] = make_float4(cs0, cs1, cs2, cs3);
  __syncthreads();
  if (threadIdx.x < 32) {
    float4 a = SS[threadIdx.x];
    for (int g = 1; g < 8; ++g) {
      float4 u = SS[g * 32 + threadIdx.x];
      a.x += u.x; a.y += u.y; a.z += u.z; a.w += u.w;
    }
    *(float4*)(pp + (size_t)blockIdx.x * 128 + threadIdx.x * 4) = a;
  }
}

__global__ void value_kernel(const float* __restrict__ pp, int nbP,
                             const void* __restrict__ vW1, const void* __restrict__ vb1,
                             const void* __restrict__ vW2, const void* __restrict__ vb2,
                             const int* __restrict__ fflag,
                             void* __restrict__ out, int n, float inv_n) {
  __shared__ float gs[128];
  int fb = *fflag;
  int c = threadIdx.x;  // 128 threads
  float s = 0.f;
#pragma unroll 8
  for (int b = 0; b < nbP; ++b) s += pp[(size_t)b * 128 + c];
  gs[c] = s;
  __syncthreads();
  if (c < 64) {
    float acc = ldf(vb1, c, fb);
    for (int k = 0; k < 128; ++k) acc = fmaf(gs[k] * inv_n, ldf(vW1, (size_t)k * 64 + c, fb), acc);
    acc = fmaxf(acc, 0.f);
    float v = acc * ldf(vW2, c, fb);
    for (int off = 32; off; off >>= 1) v += __shfl_down(v, off, 64);
    if (c == 0) {
      float r = tanhf(v + ldf(vb2, 0, fb));
      if (fb) ((bf16*)out)[n] = __float2bfloat16(r);
      else    ((float*)out)[n] = r;
    }
  }
}

// ---------------- host ----------------

extern "C" void kernel_launch(void* const* d_in, const int* in_sizes, int n_in,
                              void* d_out, int out_size, void* d_ws, size_t ws_size,
                              hipStream_t stream) {
  const void* x       = d_in[0];
  const void* ei      = d_in[1];
  const void* in_W    = d_in[3];
  const void* in_b    = d_in[4];
  const void* in_g    = d_in[5];
  const void* in_beta = d_in[6];
  const void* conv_W  = d_in[7];
  const void* conv_b  = d_in[8];
  const void* bn_g    = d_in[9];
  const void* bn_beta = d_in[10];
  const void* pW1     = d_in[11];
  const void* pb1     = d_in[12];
  const void* pW2     = d_in[13];
  const void* pb2     = d_in[14];
  const void* vW1     = d_in[15];
  const void* vb1     = d_in[16];
  const void* vW2     = d_in[17];
  const void* vb2     = d_in[18];

  const int H = 128;
  int in_dim = in_sizes[3] / H;        // 5
  int n      = in_sizes[0] / in_dim;   // 100000
  int e      = in_sizes[1] / 2;        // 3200000
  int L      = in_sizes[7] / (H * H);  // 6

  const int GS  = 2048;  // gather grid (multiple of 8)
  const int GI  = 512;   // inproj grid
  const int GP  = 1024;  // policy grid
  const int GF  = 2048;  // fill/deg grid (multiple of 8)

  char* w = (char*)d_ws;
  u16*   u    = (u16*)w;   w += (size_t)n * H * sizeof(u16);
  float* pre  = (float*)w; w += (size_t)n * H * sizeof(float);
  float* hbuf = (float*)w; w += (size_t)n * H * sizeof(float);
  int*   csr_src  = (int*)w;   w += ((size_t)e + 16) * sizeof(int);
  int*   row_ptr  = (int*)w;   w += (size_t)(n + 1 + 15) / 16 * 16 * sizeof(int);
  int*   degcnt   = (int*)w;   w += (size_t)n * sizeof(int);
  int*   fillc    = (int*)w;   w += (size_t)n * sizeof(int);
  float* dinv     = (float*)w; w += (size_t)n * sizeof(float);
  float* scale = (float*)w; w += 128 * sizeof(float);
  float* shift = (float*)w; w += 128 * sizeof(float);
  int*   eflag = (int*)w;   w += 16 * sizeof(int);
  int*   fflag = (int*)w;   w += 16 * sizeof(int);
  int*   bsum  = (int*)w;   w += 256 * sizeof(int);
  u16*   wf    = (u16*)w;   w += (size_t)L * H * H * sizeof(u16);
  float* pi    = (float*)w; w += (size_t)GI * 256 * sizeof(float);
  float* pg    = (float*)w; w += (size_t)GS * 32 * sizeof(float);
  float* pp    = (float*)w; w += (size_t)GP * 128 * sizeof(float);

  int gN = (n + 255) / 256;
  int nb = (n + 1023) >> 10;
  float inv_n = 1.0f / (float)n;

  detect_int_kernel<<<1, 256, 0, stream>>>((const int*)ei, eflag);
  detect_float_kernel<<<1, 64, 0, stream>>>((const unsigned int*)in_g, fflag);
  init_zero_kernel<<<gN, 256, 0, stream>>>(degcnt, fillc, n);
  deg_kernel<<<GF, 256, 0, stream>>>(ei, eflag, degcnt, e, n);
  dinv_kernel<<<gN, 256, 0, stream>>>(degcnt, dinv, n);
  scanA_kernel<<<nb, 256, 0, stream>>>(degcnt, row_ptr, bsum, n);
  scanB_kernel<<<1, 256, 0, stream>>>(bsum, row_ptr, nb, n, e);
  scanC_kernel<<<gN, 256, 0, stream>>>(row_ptr, bsum, n);
  fill_kernel<<<GF, 256, 0, stream>>>(ei, eflag, row_ptr, fillc, csr_src, e, n);
  wfrag_kernel<<<(L * H * H + 255) / 256, 256, 0, stream>>>(conv_W, fflag, wf, L * H * H);

  inproj_stats_kernel<<<GI, 256, 0, stream>>>(x, in_W, in_b, fflag, pre, pi, n, in_dim);
  finalize_inproj_kernel<<<1, 128, 0, stream>>>(pi, GI, in_g, in_beta, fflag, scale, shift, inv_n);

  for (int l = 0; l < L; ++l) {
    gemm_bn_kernel<<<2048, 256, 0, stream>>>(pre, hbuf, scale, shift, wf + (size_t)l * H * H,
                                             dinv, u, n, (l > 0) ? 1 : 0);
    gather_stats_kernel<<<GS, 256, 0, stream>>>(row_ptr, csr_src, u, dinv,
                                                conv_b, fflag, pre, pg, n, (size_t)l * H);
    finalize_gather_kernel<<<1, 128, 0, stream>>>(pg, GS, bn_g, bn_beta, fflag, scale, shift,
                                                  inv_n, (size_t)l * H);
  }

  policy_pool_kernel<<<GP, 256, 0, stream>>>(pre, hbuf, scale, shift, pW1, pb1, pW2, pb2,
                                             fflag, pp, d_out, n);
  value_kernel<<<1, 128, 0, stream>>>(pp, GP, vW1, vb1, vW2, vb2, fflag, d_out, n, inv_n);
}

// Round 15
// 2123.397 us; speedup vs baseline: 1.3683x; 1.0233x over previous
//
#include <hip/hip_runtime.h>
#include <hip/hip_bf16.h>

typedef __hip_bfloat16 bf16;
typedef long long i64;
typedef unsigned short u16;
typedef __attribute__((ext_vector_type(8))) short bf16x8;   // MFMA A/B frag (8 bf16)
typedef __attribute__((ext_vector_type(4))) float f32x4;    // MFMA C/D frag

#define EPSV 1e-5f
#define WINLEN 6144   // staged csr window (24 KB LDS)

static __device__ __forceinline__ float ldf(const void* p, size_t i, int fb) {
  return fb ? __bfloat162float(((const bf16*)p)[i]) : ((const float*)p)[i];
}
static __device__ __forceinline__ u16 f2b(float f) {  // RNE f32->bf16 raw bits
  unsigned int u = __float_as_uint(f);
  u += 0x7FFF + ((u >> 16) & 1);
  return (u16)(u >> 16);
}
static __device__ __forceinline__ float rb2f(u16 u) {
  return __uint_as_float(((unsigned int)u) << 16);
}

// ---------------- merged detectors + zero-init ----------------

__global__ void setup_kernel(const int* __restrict__ ei_w, const unsigned int* __restrict__ g,
                             int* __restrict__ eflag, int* __restrict__ fflag,
                             int* __restrict__ degcnt, int* __restrict__ fill, int n) {
  int i = blockIdx.x * 256 + threadIdx.x;
  if (i < n) { degcnt[i] = 0; fill[i] = 0; }
  if (blockIdx.x == 0) {
    __shared__ int nz;
    if (threadIdx.x == 0) nz = 0;
    __syncthreads();
    for (int k = threadIdx.x; k < 1024; k += 256)
      if (ei_w[2 * k + 1] != 0) atomicAdd(&nz, 1);
    __syncthreads();
    if (threadIdx.x == 0) {
      *eflag = (nz == 0) ? 1 : 0;                 // 1 => int64
      *fflag = (g[0] == 0x3F803F80u) ? 1 : 0;     // 1 => bf16
    }
  }
}

// XCD dst-partitioned: slice k = blockIdx&7 handles dst in [lo,hi).
__global__ void deg_kernel(const void* __restrict__ ei, const int* __restrict__ flag,
                           int* __restrict__ degcnt, int e, int n) {
  int k = blockIdx.x & 7;
  int lo = (int)(((long long)n * k) >> 3);
  int hi = (int)(((long long)n * (k + 1)) >> 3);
  int stride = (gridDim.x >> 3) * 256;
  int fb64 = *flag;
  for (int i = (blockIdx.x >> 3) * 256 + threadIdx.x; i < e; i += stride) {
    int d;
    if (fb64) d = (int)((const i64*)ei)[(size_t)e + i];
    else      d = ((const int*)ei)[(size_t)e + i];
    if (d >= lo && d < hi) atomicAdd(&degcnt[d], 1);
  }
}

// ---- multi-block exclusive scan (dinv folded into A) ----

__global__ void __launch_bounds__(256) scanA_kernel(const int* __restrict__ deg,
                                                    int* __restrict__ rp,
                                                    int* __restrict__ bsum,
                                                    float* __restrict__ dinv, int n) {
  int base = blockIdx.x * 1024 + threadIdx.x * 4;
  int v0 = (base     < n) ? deg[base]     : 0;
  int v1 = (base + 1 < n) ? deg[base + 1] : 0;
  int v2 = (base + 2 < n) ? deg[base + 2] : 0;
  int v3 = (base + 3 < n) ? deg[base + 3] : 0;
  if (base     < n) dinv[base]     = rsqrtf((float)v0 + 1.0f);
  if (base + 1 < n) dinv[base + 1] = rsqrtf((float)v1 + 1.0f);
  if (base + 2 < n) dinv[base + 2] = rsqrtf((float)v2 + 1.0f);
  if (base + 3 < n) dinv[base + 3] = rsqrtf((float)v3 + 1.0f);
  int ts = v0 + v1 + v2 + v3;
  __shared__ int ls[256];
  ls[threadIdx.x] = ts;
  __syncthreads();
  for (int off = 1; off < 256; off <<= 1) {
    int u = (threadIdx.x >= off) ? ls[threadIdx.x - off] : 0;
    __syncthreads();
    ls[threadIdx.x] += u;
    __syncthreads();
  }
  int run = ls[threadIdx.x] - ts;
  if (base     < n) rp[base]     = run; run += v0;
  if (base + 1 < n) rp[base + 1] = run; run += v1;
  if (base + 2 < n) rp[base + 2] = run; run += v2;
  if (base + 3 < n) rp[base + 3] = run;
  if (threadIdx.x == 255) bsum[blockIdx.x] = ls[255];
}

__global__ void __launch_bounds__(256) scanB_kernel(int* __restrict__ bsum, int* __restrict__ rp,
                                                    int nb, int n, int e) {
  __shared__ int ls[256];
  int t = threadIdx.x;
  int v = (t < nb) ? bsum[t] : 0;
  ls[t] = v;
  __syncthreads();
  for (int off = 1; off < 256; off <<= 1) {
    int u = (t >= off) ? ls[t - off] : 0;
    __syncthreads();
    ls[t] += u;
    __syncthreads();
  }
  if (t < nb) bsum[t] = ls[t] - v;  // exclusive
  if (t == 0) rp[n] = e;
}

__global__ void scanC_kernel(int* __restrict__ rp, const int* __restrict__ bsum, int n) {
  int i = blockIdx.x * 256 + threadIdx.x;
  if (i < n) rp[i] += bsum[i >> 10];
}

// XCD dst-partitioned fill.
__global__ void fill_kernel(const void* __restrict__ ei, const int* __restrict__ flag,
                            const int* __restrict__ row_ptr,
                            int* __restrict__ fill, int* __restrict__ csr_src, int e, int n) {
  int k = blockIdx.x & 7;
  int lo = (int)(((long long)n * k) >> 3);
  int hi = (int)(((long long)n * (k + 1)) >> 3);
  int stride = (gridDim.x >> 3) * 256;
  int fb64 = *flag;
  for (int i = (blockIdx.x >> 3) * 256 + threadIdx.x; i < e; i += stride) {
    int d;
    if (fb64) d = (int)((const i64*)ei)[(size_t)e + i];
    else      d = ((const int*)ei)[(size_t)e + i];
    if (d < lo || d >= hi) continue;
    int s;
    if (fb64) s = (int)((const i64*)ei)[i];
    else      s = ((const int*)ei)[i];
    int pos = row_ptr[d] + atomicAdd(&fill[d], 1);
    csr_src[pos] = s;
  }
}

// ---------------- conv_W -> global B-frag order (bf16) ----------------

__global__ void wfrag_kernel(const void* __restrict__ W, const int* __restrict__ fflag,
                             u16* __restrict__ wf, int total) {
  int fb = *fflag;
  int i = blockIdx.x * 256 + threadIdx.x;
  if (i >= total) return;
  int l = i >> 14, r = i & 16383;
  int k = r >> 7, nn = r & 127;
  int s = k >> 5, quad = (k >> 3) & 3, j = k & 7;
  int ct = nn >> 4, n16 = nn & 15;
  wf[(size_t)l * 16384 + (ct * 4 + s) * 512 + quad * 128 + n16 * 8 + j] = f2b(ldf(W, i, fb));
}

// ---------------- input projection + BN partial stats (no atomics) ----------------

__global__ void __launch_bounds__(256) inproj_stats_kernel(
    const void* __restrict__ x, const void* __restrict__ W, const void* __restrict__ b,
    const int* __restrict__ fflag, float* __restrict__ pre,
    float* __restrict__ pi, int n, int in_dim) {
  int fb = *fflag;
  int q = threadIdx.x & 31, g8 = threadIdx.x >> 5;
  int c = q * 4;
  float b0 = ldf(b, c, fb), b1 = ldf(b, c + 1, fb), b2v = ldf(b, c + 2, fb), b3 = ldf(b, c + 3, fb);
  float s0 = 0, s1 = 0, s2 = 0, s3 = 0, q0 = 0, q1 = 0, q2 = 0, q3 = 0;
  for (int node = blockIdx.x * 8 + g8; node < n; node += gridDim.x * 8) {
    float a0 = b0, a1 = b1, a2 = b2v, a3 = b3;
    for (int k = 0; k < in_dim; ++k) {
      float xv = ldf(x, (size_t)node * in_dim + k, fb);
      size_t w0 = (size_t)k * 128 + c;
      a0 = fmaf(xv, ldf(W, w0, fb), a0);
      a1 = fmaf(xv, ldf(W, w0 + 1, fb), a1);
      a2 = fmaf(xv, ldf(W, w0 + 2, fb), a2);
      a3 = fmaf(xv, ldf(W, w0 + 3, fb), a3);
    }
    *(float4*)(pre + (size_t)node * 128 + c) = make_float4(a0, a1, a2, a3);
    s0 += a0; s1 += a1; s2 += a2; s3 += a3;
    q0 = fmaf(a0, a0, q0); q1 = fmaf(a1, a1, q1); q2 = fmaf(a2, a2, q2); q3 = fmaf(a3, a3, q3);
  }
  __shared__ float4 SS[256], QQ[256];
  SS[threadIdx.x] = make_float4(s0, s1, s2, s3);
  QQ[threadIdx.x] = make_float4(q0, q1, q2, q3);
  __syncthreads();
  if (threadIdx.x < 32) {
    float4 a = SS[threadIdx.x], qq = QQ[threadIdx.x];
    for (int g = 1; g < 8; ++g) {
      float4 u = SS[g * 32 + threadIdx.x], w = QQ[g * 32 + threadIdx.x];
      a.x += u.x; a.y += u.y; a.z += u.z; a.w += u.w;
      qq.x += w.x; qq.y += w.y; qq.z += w.z; qq.w += w.w;
    }
    int cc = threadIdx.x * 4;
    *(float4*)(pi + (size_t)blockIdx.x * 256 + cc) = a;
    *(float4*)(pi + (size_t)blockIdx.x * 256 + 128 + cc) = qq;
  }
}

__global__ void finalize_inproj_kernel(const float* __restrict__ pi, int nb,
                                       const void* __restrict__ g, const void* __restrict__ beta,
                                       const int* __restrict__ fflag,
                                       float* __restrict__ scale, float* __restrict__ shift,
                                       float inv_n) {
  int fb = *fflag;
  int c = threadIdx.x;  // 128
  float s = 0.f, s2 = 0.f;
#pragma unroll 4
  for (int b = 0; b < nb; ++b) {
    s += pi[(size_t)b * 256 + c];
    s2 += pi[(size_t)b * 256 + 128 + c];
  }
  float mean = s * inv_n;
  float var = s2 * inv_n - mean * mean;
  float sc = ldf(g, c, fb) * rsqrtf(var + EPSV);
  scale[c] = sc;
  shift[c] = ldf(beta, c, fb) - mean * sc;
}

// ---------------- fused BN-apply(+residual) + MFMA GEMM (bf16), norm-folded ----------------
// u stored SLICE-MAJOR: u[ct][node][16] for XCD cache blocking.

__global__ void __launch_bounds__(256) gemm_bn_kernel(
    const float* __restrict__ pre, float* __restrict__ hbuf,
    const float* __restrict__ scale, const float* __restrict__ shift,
    const u16* __restrict__ wfL, const float* __restrict__ dinv,
    u16* __restrict__ u, int n, int use_res) {
  __shared__ u16 At[4][2048];   // per-wave A tile in frag order: s*512 + lane*8
  int lane = threadIdx.x & 63;
  int wave = threadIdx.x >> 6;
  int n16 = lane & 15, quad = lane >> 4;
  u16* at = At[wave];
  int node = lane & 15;             // staging row
  int cgrp = lane >> 4;             // staging col group 0..3
  int ntiles = (n + 15) >> 4;
  for (int tile = blockIdx.x * 4 + wave; tile < ntiles; tile += gridDim.x * 4) {
    int n0 = tile * 16;
    int gn = n0 + node;
    // ---- stage hnew tile (frag order) ----
#pragma unroll
    for (int r = 0; r < 8; ++r) {
      int c4 = r * 4 + cgrp;        // 0..31
      int c = c4 * 4;
      float4 h4 = make_float4(0.f, 0.f, 0.f, 0.f);
      if (gn < n) {
        float4 p = *(const float4*)(pre + (size_t)gn * 128 + c);
        float4 sc = *(const float4*)(scale + c);
        float4 sh = *(const float4*)(shift + c);
        h4.x = fmaxf(fmaf(p.x, sc.x, sh.x), 0.f);
        h4.y = fmaxf(fmaf(p.y, sc.y, sh.y), 0.f);
        h4.z = fmaxf(fmaf(p.z, sc.z, sh.z), 0.f);
        h4.w = fmaxf(fmaf(p.w, sc.w, sh.w), 0.f);
        if (use_res) {
          float4 rv = *(const float4*)(hbuf + (size_t)gn * 128 + c);
          h4.x += rv.x; h4.y += rv.y; h4.z += rv.z; h4.w += rv.w;
        }
        *(float4*)(hbuf + (size_t)gn * 128 + c) = h4;
      }
      ushort4 uu;
      uu.x = f2b(h4.x); uu.y = f2b(h4.y); uu.z = f2b(h4.z); uu.w = f2b(h4.w);
      int s = c4 >> 3, qd = (c4 >> 1) & 3, j0 = (c4 & 1) * 4;
      *(ushort4*)(at + s * 512 + qd * 128 + node * 8 + j0) = uu;
    }
    __builtin_amdgcn_s_waitcnt(0);  // drain LDS writes (wave-local tile)
    // ---- MFMA: 4 K-steps x 8 col-tiles; B from global wf ----
    f32x4 acc[8];
#pragma unroll
    for (int ct = 0; ct < 8; ++ct) acc[ct] = (f32x4){0.f, 0.f, 0.f, 0.f};
#pragma unroll
    for (int s = 0; s < 4; ++s) {
      bf16x8 af = *(const bf16x8*)(at + s * 512 + lane * 8);
#pragma unroll
      for (int ct = 0; ct < 8; ++ct) {
        bf16x8 bfr = *(const bf16x8*)(wfL + (size_t)(ct * 4 + s) * 512 + lane * 8);
        acc[ct] = __builtin_amdgcn_mfma_f32_16x16x32_bf16(af, bfr, acc[ct], 0, 0, 0);
      }
    }
    // ---- store D scaled by dinv[row], slice-major ----
    float dv[4];
#pragma unroll
    for (int r = 0; r < 4; ++r) {
      int row = n0 + quad * 4 + r;
      dv[r] = (row < n) ? dinv[row] : 0.f;
    }
#pragma unroll
    for (int ct = 0; ct < 8; ++ct) {
#pragma unroll
      for (int r = 0; r < 4; ++r) {
        int row = n0 + quad * 4 + r;
        if (row < n) u[((size_t)ct * n + row) * 16 + n16] = f2b(acc[ct][r] * dv[r]);
      }
    }
  }
}

// ---------------- fused gather, XCD-sliced, LDS-staged nt csr, partial stats ----------------
// 8-deep load pipeline per thread for memory-level parallelism.

__global__ void __launch_bounds__(256) gather_stats_kernel(
    const int* __restrict__ row_ptr, const int* __restrict__ csr_src,
    const u16* __restrict__ u, const float* __restrict__ dinv,
    const void* __restrict__ b, const int* __restrict__ fflag,
    float* __restrict__ pre, float* __restrict__ pg, int n, size_t bOff) {
  __shared__ int sm[WINLEN];
  __shared__ float SW[4][2][8], QW[4][2][8];
  int fb = *fflag;
  int ct = blockIdx.x & 7;
  const u16* us = u + (size_t)ct * n * 16;
  int q = threadIdx.x & 1;           // 16B half
  int g = threadIdx.x >> 1;          // node group 0..127
  int c = ct * 16 + q * 8;           // global channel base
  float bias[8];
#pragma unroll
  for (int i = 0; i < 8; ++i) bias[i] = ldf(b, bOff + c + i, fb);
  float sA[8], qA[8];
#pragma unroll
  for (int i = 0; i < 8; ++i) { sA[i] = 0.f; qA[i] = 0.f; }

  int chunk_stride = (gridDim.x >> 3) * 128;
  for (int c0 = (blockIdx.x >> 3) * 128; c0 < n; c0 += chunk_stride) {
    int node = c0 + g;
    int valid = node < n;
    int beg = valid ? row_ptr[node] : 0;
    int end = valid ? row_ptr[node + 1] : 0;
    int cend = c0 + 128; if (cend > n) cend = n;
    int chunk_lo = row_ptr[c0];
    int chunk_hi = row_ptr[cend];
    float acc[8];
    if (valid) {
      ushort4 su = *(const ushort4*)(us + (size_t)node * 16 + q * 8);
      acc[0] = rb2f(su.x); acc[1] = rb2f(su.y); acc[2] = rb2f(su.z); acc[3] = rb2f(su.w);
      ushort4 su2 = *(const ushort4*)(us + (size_t)node * 16 + q * 8 + 4);
      acc[4] = rb2f(su2.x); acc[5] = rb2f(su2.y); acc[6] = rb2f(su2.z); acc[7] = rb2f(su2.w);
    } else {
#pragma unroll
      for (int i = 0; i < 8; ++i) acc[i] = 0.f;
    }
    for (int wlo = chunk_lo; wlo < chunk_hi; wlo += WINLEN) {
      int wlen = chunk_hi - wlo; if (wlen > WINLEN) wlen = WINLEN;
      __syncthreads();   // previous window fully consumed
      for (int i = threadIdx.x; i < wlen; i += 256)
        sm[i] = __builtin_nontemporal_load(csr_src + wlo + i);
      __syncthreads();
      int j0 = beg > wlo ? beg : wlo;
      int j1 = end < wlo + wlen ? end : wlo + wlen;
      int j = j0;
#define ACC(UU) \
      acc[0] += __uint_as_float(UU.x << 16); acc[1] += __uint_as_float(UU.x & 0xFFFF0000u); \
      acc[2] += __uint_as_float(UU.y << 16); acc[3] += __uint_as_float(UU.y & 0xFFFF0000u); \
      acc[4] += __uint_as_float(UU.z << 16); acc[5] += __uint_as_float(UU.z & 0xFFFF0000u); \
      acc[6] += __uint_as_float(UU.w << 16); acc[7] += __uint_as_float(UU.w & 0xFFFF0000u);
      for (; j + 8 <= j1; j += 8) {
        int i0 = sm[j - wlo],     i1 = sm[j - wlo + 1], i2 = sm[j - wlo + 2], i3 = sm[j - wlo + 3];
        int i4 = sm[j - wlo + 4], i5 = sm[j - wlo + 5], i6 = sm[j - wlo + 6], i7 = sm[j - wlo + 7];
        uint4 U0 = *(const uint4*)(us + (size_t)i0 * 16 + q * 8);
        uint4 U1 = *(const uint4*)(us + (size_t)i1 * 16 + q * 8);
        uint4 U2 = *(const uint4*)(us + (size_t)i2 * 16 + q * 8);
        uint4 U3 = *(const uint4*)(us + (size_t)i3 * 16 + q * 8);
        uint4 U4 = *(const uint4*)(us + (size_t)i4 * 16 + q * 8);
        uint4 U5 = *(const uint4*)(us + (size_t)i5 * 16 + q * 8);
        uint4 U6 = *(const uint4*)(us + (size_t)i6 * 16 + q * 8);
        uint4 U7 = *(const uint4*)(us + (size_t)i7 * 16 + q * 8);
        ACC(U0) ACC(U1) ACC(U2) ACC(U3) ACC(U4) ACC(U5) ACC(U6) ACC(U7)
      }
      for (; j + 4 <= j1; j += 4) {
        int i0 = sm[j - wlo], i1 = sm[j - wlo + 1], i2 = sm[j - wlo + 2], i3 = sm[j - wlo + 3];
        uint4 U0 = *(const uint4*)(us + (size_t)i0 * 16 + q * 8);
        uint4 U1 = *(const uint4*)(us + (size_t)i1 * 16 + q * 8);
        uint4 U2 = *(const uint4*)(us + (size_t)i2 * 16 + q * 8);
        uint4 U3 = *(const uint4*)(us + (size_t)i3 * 16 + q * 8);
        ACC(U0) ACC(U1) ACC(U2) ACC(U3)
      }
      for (; j < j1; ++j) {
        int i0 = sm[j - wlo];
        uint4 U0 = *(const uint4*)(us + (size_t)i0 * 16 + q * 8);
        ACC(U0)
      }
#undef ACC
    }
    if (valid) {
      float dv = dinv[node];
      float4 o0, o1;
      o0.x = fmaf(acc[0], dv, bias[0]); o0.y = fmaf(acc[1], dv, bias[1]);
      o0.z = fmaf(acc[2], dv, bias[2]); o0.w = fmaf(acc[3], dv, bias[3]);
      o1.x = fmaf(acc[4], dv, bias[4]); o1.y = fmaf(acc[5], dv, bias[5]);
      o1.z = fmaf(acc[6], dv, bias[6]); o1.w = fmaf(acc[7], dv, bias[7]);
      *(float4*)(pre + (size_t)node * 128 + c) = o0;
      *(float4*)(pre + (size_t)node * 128 + c + 4) = o1;
      sA[0] += o0.x; sA[1] += o0.y; sA[2] += o0.z; sA[3] += o0.w;
      sA[4] += o1.x; sA[5] += o1.y; sA[6] += o1.z; sA[7] += o1.w;
      qA[0] = fmaf(o0.x, o0.x, qA[0]); qA[1] = fmaf(o0.y, o0.y, qA[1]);
      qA[2] = fmaf(o0.z, o0.z, qA[2]); qA[3] = fmaf(o0.w, o0.w, qA[3]);
      qA[4] = fmaf(o1.x, o1.x, qA[4]); qA[5] = fmaf(o1.y, o1.y, qA[5]);
      qA[6] = fmaf(o1.z, o1.z, qA[6]); qA[7] = fmaf(o1.w, o1.w, qA[7]);
    }
  }
  // wave butterfly over node-groups (keep q invariant: xor masks even)
#pragma unroll
  for (int m = 2; m <= 32; m <<= 1) {
#pragma unroll
    for (int i = 0; i < 8; ++i) {
      sA[i] += __shfl_xor(sA[i], m, 64);
      qA[i] += __shfl_xor(qA[i], m, 64);
    }
  }
  int lane = threadIdx.x & 63, wv = threadIdx.x >> 6;
  if (lane < 2) {
#pragma unroll
    for (int i = 0; i < 8; ++i) { SW[wv][lane][i] = sA[i]; QW[wv][lane][i] = qA[i]; }
  }
  __syncthreads();
  if (threadIdx.x < 16) {
    int qq = threadIdx.x >> 3, i = threadIdx.x & 7;
    float a = SW[0][qq][i] + SW[1][qq][i] + SW[2][qq][i] + SW[3][qq][i];
    float b2 = QW[0][qq][i] + QW[1][qq][i] + QW[2][qq][i] + QW[3][qq][i];
    pg[(size_t)blockIdx.x * 32 + qq * 8 + i] = a;
    pg[(size_t)blockIdx.x * 32 + 16 + qq * 8 + i] = b2;
  }
}

__global__ void finalize_gather_kernel(const float* __restrict__ pg, int nbG,
                                       const void* __restrict__ g, const void* __restrict__ beta,
                                       const int* __restrict__ fflag,
                                       float* __restrict__ scale, float* __restrict__ shift,
                                       float inv_n, size_t off) {
  int fb = *fflag;
  int c = threadIdx.x;  // 128
  int ct = c >> 4, ic = c & 15;
  float s = 0.f, s2 = 0.f;
#pragma unroll 4
  for (int b = ct; b < nbG; b += 8) {
    s += pg[(size_t)b * 32 + ic];
    s2 += pg[(size_t)b * 32 + 16 + ic];
  }
  float mean = s * inv_n;
  float var = s2 * inv_n - mean * mean;
  float sc = ldf(g, off + c, fb) * rsqrtf(var + EPSV);
  scale[c] = sc;
  shift[c] = ldf(beta, off + c, fb) - mean * sc;
}

// ---------------- fused final: BN-apply + residual + policy MLP + pool partials ----------------

__global__ void __launch_bounds__(256) policy_pool_kernel(
    const float* __restrict__ pre, const float* __restrict__ hbuf,
    const float* __restrict__ scale, const float* __restrict__ shift,
    const void* __restrict__ pW1, const void* __restrict__ pb1,
    const void* __restrict__ pW2, const void* __restrict__ pb2,
    const int* __restrict__ fflag, float* __restrict__ pp,
    void* __restrict__ out, int n) {
  __shared__ float W1[128 * 32];
  __shared__ float B1v[32], W2v[32];
  int fb = *fflag;
  for (int i = threadIdx.x; i < 128 * 32; i += 256) W1[i] = ldf(pW1, i, fb);
  if (threadIdx.x < 32) {
    B1v[threadIdx.x] = ldf(pb1, threadIdx.x, fb);
    W2v[threadIdx.x] = ldf(pW2, threadIdx.x, fb);
  }
  __syncthreads();
  float bias2 = ldf(pb2, 0, fb);
  int q = threadIdx.x & 31, g8 = threadIdx.x >> 5;
  int c = q * 4;
  float4 sc = *(const float4*)(scale + c);
  float4 sh = *(const float4*)(shift + c);
  float cs0 = 0, cs1 = 0, cs2 = 0, cs3 = 0;
  for (int node = blockIdx.x * 8 + g8; node < n; node += gridDim.x * 8) {
    float4 p = *(const float4*)(pre + (size_t)node * 128 + c);
    float4 r = *(const float4*)(hbuf + (size_t)node * 128 + c);
    float4 h4;
    h4.x = fmaxf(fmaf(p.x, sc.x, sh.x), 0.f) + r.x;
    h4.y = fmaxf(fmaf(p.y, sc.y, sh.y), 0.f) + r.y;
    h4.z = fmaxf(fmaf(p.z, sc.z, sh.z), 0.f) + r.z;
    h4.w = fmaxf(fmaf(p.w, sc.w, sh.w), 0.f) + r.w;
    cs0 += h4.x; cs1 += h4.y; cs2 += h4.z; cs3 += h4.w;
    float acc = B1v[q];
#pragma unroll
    for (int k4 = 0; k4 < 32; ++k4) {
      float hx = __shfl(h4.x, k4, 32);
      float hy = __shfl(h4.y, k4, 32);
      float hz = __shfl(h4.z, k4, 32);
      float hw = __shfl(h4.w, k4, 32);
      int k = k4 * 4;
      acc = fmaf(hx, W1[k * 32 + q], acc);
      acc = fmaf(hy, W1[(k + 1) * 32 + q], acc);
      acc = fmaf(hz, W1[(k + 2) * 32 + q], acc);
      acc = fmaf(hw, W1[(k + 3) * 32 + q], acc);
    }
    acc = fmaxf(acc, 0.f) * W2v[q];
    for (int off = 16; off; off >>= 1) acc += __shfl_down(acc, off, 32);
    if (q == 0) {
      float v = acc + bias2;
      if (fb) ((bf16*)out)[node] = __float2bfloat16(v);
      else    ((float*)out)[node] = v;
    }
  }
  __shared__ float4 SS[256];
  SS[threadIdx.x] = make_float4(cs0, cs1, cs2, cs3);
  __syncthreads();
  if (threadIdx.x < 32) {
    float4 a = SS[threadIdx.x];
    for (int g = 1; g < 8; ++g) {
      float4 u = SS[g * 32 + threadIdx.x];
      a.x += u.x; a.y += u.y; a.z += u.z; a.w += u.w;
    }
    *(float4*)(pp + (size_t)blockIdx.x * 128 + threadIdx.x * 4) = a;
  }
}

__global__ void value_kernel(const float* __restrict__ pp, int nbP,
                             const void* __restrict__ vW1, const void* __restrict__ vb1,
                             const void* __restrict__ vW2, const void* __restrict__ vb2,
                             const int* __restrict__ fflag,
                             void* __restrict__ out, int n, float inv_n) {
  __shared__ float gs[128];
  int fb = *fflag;
  int c = threadIdx.x;  // 128 threads
  float s = 0.f;
#pragma unroll 8
  for (int b = 0; b < nbP; ++b) s += pp[(size_t)b * 128 + c];
  gs[c] = s;
  __syncthreads();
  if (c < 64) {
    float acc = ldf(vb1, c, fb);
    for (int k = 0; k < 128; ++k) acc = fmaf(gs[k] * inv_n, ldf(vW1, (size_t)k * 64 + c, fb), acc);
    acc = fmaxf(acc, 0.f);
    float v = acc * ldf(vW2, c, fb);
    for (int off = 32; off; off >>= 1) v += __shfl_down(v, off, 64);
    if (c == 0) {
      float r = tanhf(v + ldf(vb2, 0, fb));
      if (fb) ((bf16*)out)[n] = __float2bfloat16(r);
      else    ((float*)out)[n] = r;
    }
  }
}

// ---------------- host ----------------

extern "C" void kernel_launch(void* const* d_in, const int* in_sizes, int n_in,
                              void* d_out, int out_size, void* d_ws, size_t ws_size,
                              hipStream_t stream) {
  const void* x       = d_in[0];
  const void* ei      = d_in[1];
  const void* in_W    = d_in[3];
  const void* in_b    = d_in[4];
  const void* in_g    = d_in[5];
  const void* in_beta = d_in[6];
  const void* conv_W  = d_in[7];
  const void* conv_b  = d_in[8];
  const void* bn_g    = d_in[9];
  const void* bn_beta = d_in[10];
  const void* pW1     = d_in[11];
  const void* pb1     = d_in[12];
  const void* pW2     = d_in[13];
  const void* pb2     = d_in[14];
  const void* vW1     = d_in[15];
  const void* vb1     = d_in[16];
  const void* vW2     = d_in[17];
  const void* vb2     = d_in[18];

  const int H = 128;
  int in_dim = in_sizes[3] / H;        // 5
  int n      = in_sizes[0] / in_dim;   // 100000
  int e      = in_sizes[1] / 2;        // 3200000
  int L      = in_sizes[7] / (H * H);  // 6

  const int GS  = 2048;  // gather grid (multiple of 8)
  const int GI  = 512;   // inproj grid
  const int GP  = 1024;  // policy grid
  const int GF  = 2048;  // fill/deg grid (multiple of 8)

  char* w = (char*)d_ws;
  u16*   u    = (u16*)w;   w += (size_t)n * H * sizeof(u16);
  float* pre  = (float*)w; w += (size_t)n * H * sizeof(float);
  float* hbuf = (float*)w; w += (size_t)n * H * sizeof(float);
  int*   csr_src  = (int*)w;   w += ((size_t)e + 16) * sizeof(int);
  int*   row_ptr  = (int*)w;   w += (size_t)(n + 1 + 15) / 16 * 16 * sizeof(int);
  int*   degcnt   = (int*)w;   w += (size_t)n * sizeof(int);
  int*   fillc    = (int*)w;   w += (size_t)n * sizeof(int);
  float* dinv     = (float*)w; w += (size_t)n * sizeof(float);
  float* scale = (float*)w; w += 128 * sizeof(float);
  float* shift = (float*)w; w += 128 * sizeof(float);
  int*   eflag = (int*)w;   w += 16 * sizeof(int);
  int*   fflag = (int*)w;   w += 16 * sizeof(int);
  int*   bsum  = (int*)w;   w += 256 * sizeof(int);
  u16*   wf    = (u16*)w;   w += (size_t)L * H * H * sizeof(u16);
  float* pi    = (float*)w; w += (size_t)GI * 256 * sizeof(float);
  float* pg    = (float*)w; w += (size_t)GS * 32 * sizeof(float);
  float* pp    = (float*)w; w += (size_t)GP * 128 * sizeof(float);

  int gN = (n + 255) / 256;
  int nb = (n + 1023) >> 10;
  float inv_n = 1.0f / (float)n;

  setup_kernel<<<gN, 256, 0, stream>>>((const int*)ei, (const unsigned int*)in_g,
                                       eflag, fflag, degcnt, fillc, n);
  deg_kernel<<<GF, 256, 0, stream>>>(ei, eflag, degcnt, e, n);
  scanA_kernel<<<nb, 256, 0, stream>>>(degcnt, row_ptr, bsum, dinv, n);
  scanB_kernel<<<1, 256, 0, stream>>>(bsum, row_ptr, nb, n, e);
  scanC_kernel<<<gN, 256, 0, stream>>>(row_ptr, bsum, n);
  fill_kernel<<<GF, 256, 0, stream>>>(ei, eflag, row_ptr, fillc, csr_src, e, n);
  wfrag_kernel<<<(L * H * H + 255) / 256, 256, 0, stream>>>(conv_W, fflag, wf, L * H * H);

  inproj_stats_kernel<<<GI, 256, 0, stream>>>(x, in_W, in_b, fflag, pre, pi, n, in_dim);
  finalize_inproj_kernel<<<1, 128, 0, stream>>>(pi, GI, in_g, in_beta, fflag, scale, shift, inv_n);

  for (int l = 0; l < L; ++l) {
    gemm_bn_kernel<<<2048, 256, 0, stream>>>(pre, hbuf, scale, shift, wf + (size_t)l * H * H,
                                             dinv, u, n, (l > 0) ? 1 : 0);
    gather_stats_kernel<<<GS, 256, 0, stream>>>(row_ptr, csr_src, u, dinv,
                                                conv_b, fflag, pre, pg, n, (size_t)l * H);
    finalize_gather_kernel<<<1, 128, 0, stream>>>(pg, GS, bn_g, bn_beta, fflag, scale, shift,
                                                  inv_n, (size_t)l * H);
  }

  policy_pool_kernel<<<GP, 256, 0, stream>>>(pre, hbuf, scale, shift, pW1, pb1, pW2, pb2,
                                             fflag, pp, d_out, n);
  value_kernel<<<1, 128, 0, stream>>>(pp, GP, vW1, vb1, vW2, vb2, fflag, d_out, n, inv_n);
}